// Round 16
// baseline (698.351 us; speedup 1.0000x reference)
//
#include <hip/hip_runtime.h>

#define EMB 300
#define HID 600
#define NL 5
#define BN_EPS 1e-5f

#define FS 320          // padded feature stride (300 -> 320); row = 640 B
#define HS 640          // padded hidden stride (600 -> 640)
#define NPW 8           // nodes per wave in k_aggregate
#define KS1 10          // GEMM1 K-steps (320/32)
#define KS2 20          // GEMM2 K-steps (640/32)

typedef __attribute__((ext_vector_type(8))) short short8;
typedef __attribute__((ext_vector_type(4))) float f32x4;
typedef __attribute__((ext_vector_type(4))) unsigned short us4;

__device__ __forceinline__ unsigned short f2bf(float x) {
    unsigned u = __float_as_uint(x);
    unsigned r = (u + 0x7FFFu + ((u >> 16) & 1u)) >> 16;   // RNE
    return (unsigned short)r;
}
__device__ __forceinline__ float bf2f(unsigned short h) {
    return __uint_as_float(((unsigned)h) << 16);
}

#define GLDS16(gsrc, ldst)                                                     \
    __builtin_amdgcn_global_load_lds(                                          \
        (const __attribute__((address_space(1))) unsigned int*)(gsrc),         \
        (__attribute__((address_space(3))) unsigned int*)(ldst), 16, 0, 0)

// pinned-issue 16B weight load (prefetch the compiler refuses to schedule)
#define GLOAD8(dst, ptr)                                                       \
    asm volatile("global_load_dwordx4 %0, %1, off" : "=v"(dst) : "v"(ptr))

#define MFMA(d, w, a) d = __builtin_amdgcn_mfma_f32_16x16x32_bf16(w, a, d, 0, 0, 0)

// load a 2-ks weight set (10 fragments) into named register set W
#define LSET(W, P, KS)                                                         \
    GLOAD8(W##0, P[0] + (KS) * 512); GLOAD8(W##1, P[1] + (KS) * 512);          \
    GLOAD8(W##2, P[2] + (KS) * 512); GLOAD8(W##3, P[3] + (KS) * 512);          \
    GLOAD8(W##4, P[4] + (KS) * 512);                                           \
    GLOAD8(W##5, P[0] + ((KS) + 1) * 512); GLOAD8(W##6, P[1] + ((KS) + 1) * 512); \
    GLOAD8(W##7, P[2] + ((KS) + 1) * 512); GLOAD8(W##8, P[3] + ((KS) + 1) * 512); \
    GLOAD8(W##9, P[4] + ((KS) + 1) * 512);

#define WAITK do { asm volatile("s_waitcnt vmcnt(10)" ::: "memory");           \
                   __builtin_amdgcn_sched_barrier(0); } while (0)
#define WAIT0 do { asm volatile("s_waitcnt vmcnt(0)" ::: "memory");            \
                   __builtin_amdgcn_sched_barrier(0); } while (0)

// ---------------- h0 = node_emb0[an] + node_emb1[ch] -> bf16, stride FS ----------------
__global__ void k_init_h0(const int* __restrict__ an, const int* __restrict__ ch,
                          const float* __restrict__ ne0, const float* __restrict__ ne1,
                          unsigned short* __restrict__ Fb, int n) {
    int t = blockIdx.x * blockDim.x + threadIdx.x;
    int i = t / (FS / 4), f4 = t - i * (FS / 4);
    if (i >= n) return;
    int f = f4 * 4;
    us4 h = {0, 0, 0, 0};
    if (f < EMB) {  // EMB=300 is a multiple of 4; rows are 16B-aligned
        const float4 a = *(const float4*)(ne0 + (size_t)an[i] * EMB + f);
        const float4 b = *(const float4*)(ne1 + (size_t)ch[i] * EMB + f);
        h[0] = f2bf(a.x + b.x); h[1] = f2bf(a.y + b.y);
        h[2] = f2bf(a.z + b.z); h[3] = f2bf(a.w + b.w);
    }
    *(us4*)(Fb + (size_t)i * FS + f) = h;
}

// ---------------- CSR build (by dst) + per-node categorical counts [N][9] ----------------
__global__ void k_hist(const int* __restrict__ dst, const int* __restrict__ bt,
                       const int* __restrict__ bd, int* __restrict__ deg,
                       int* __restrict__ cnt9, int e) {
    int t = blockIdx.x * blockDim.x + threadIdx.x;
    if (t >= e) return;
    int d = dst[t];
    atomicAdd(&deg[d], 1);
    atomicAdd(&cnt9[d * 9 + bt[t]], 1);
    atomicAdd(&cnt9[d * 9 + 6 + bd[t]], 1);
}

// ---- hierarchical scan: pass A ----
__global__ __launch_bounds__(256)
void k_scan_blk(const int* __restrict__ deg, int* __restrict__ incl,
                int* __restrict__ part, int n) {
    int tid = threadIdx.x;
    int base = blockIdx.x * 1024 + tid * 4;
    int v0 = (base + 0 < n) ? deg[base + 0] : 0;
    int v1 = (base + 1 < n) ? deg[base + 1] : 0;
    int v2 = (base + 2 < n) ? deg[base + 2] : 0;
    int v3 = (base + 3 < n) ? deg[base + 3] : 0;
    int ts = v0 + v1 + v2 + v3;
    int lane = tid & 63, w = tid >> 6;
    int x = ts;
#pragma unroll
    for (int off = 1; off < 64; off <<= 1) {
        int y = __shfl_up(x, off);
        if (lane >= off) x += y;
    }
    __shared__ int ws[4];
    if (lane == 63) ws[w] = x;
    __syncthreads();
    int woff = 0;
    for (int i = 0; i < w; ++i) woff += ws[i];
    int r = woff + x - ts;
    r += v0; if (base + 0 < n) incl[base + 0] = r;
    r += v1; if (base + 1 < n) incl[base + 1] = r;
    r += v2; if (base + 2 < n) incl[base + 2] = r;
    r += v3; if (base + 3 < n) incl[base + 3] = r;
    if (tid == 255) part[blockIdx.x] = woff + x;
}

// ---- pass B ----
__global__ __launch_bounds__(1024)
void k_scan_part(int* __restrict__ part, int nb) {
    int tid = threadIdx.x;
    int v = (tid < nb) ? part[tid] : 0;
    int lane = tid & 63, w = tid >> 6;
    int x = v;
#pragma unroll
    for (int off = 1; off < 64; off <<= 1) {
        int y = __shfl_up(x, off);
        if (lane >= off) x += y;
    }
    __shared__ int ws[16];
    if (lane == 63) ws[w] = x;
    __syncthreads();
    int woff = 0;
    for (int i = 0; i < w; ++i) woff += ws[i];
    if (tid < nb) part[tid] = woff + x - v;
}

// ---- pass C ----
__global__ void k_scan_add(const int* __restrict__ incl, const int* __restrict__ part,
                           const int* __restrict__ deg, int* __restrict__ roff,
                           int* __restrict__ curs, int n) {
    int i = blockIdx.x * blockDim.x + threadIdx.x;
    if (i >= n) return;
    int inc = incl[i] + part[i >> 10];
    roff[i + 1] = inc;
    curs[i] = inc - deg[i];
    if (i == 0) roff[0] = 0;
}

__global__ void k_scatter(const int* __restrict__ dst, const int* __restrict__ src,
                          int* __restrict__ cursor, int* __restrict__ srcs, int e) {
    int t = blockIdx.x * blockDim.x + threadIdx.x;
    if (t < e) { int p = atomicAdd(&cursor[dst[t]], 1); srcs[p] = src[t]; }
}

// ---- graph boundaries ----
__global__ void k_gbound(const int* __restrict__ gids, int* __restrict__ gstart,
                         int n, int G) {
    int i = blockIdx.x * blockDim.x + threadIdx.x;
    if (i >= n) return;
    int g = gids[i];
    int gp = (i == 0) ? -1 : gids[i - 1];
    for (int q = gp + 1; q <= g; ++q) gstart[q] = i;
    if (i == n - 1)
        for (int q = g + 1; q <= G; ++q) gstart[q] = n;
}

// ---------------- weight prep: MFMA-fragment-packed bf16 weights ----------------
// W1P[l][nf=0..39][ks=0..KS1-1][lane][8]: frag elem = W1[l][ks*32+(lane>>4)*8+e][nf*16+(lane&15)]
__global__ void k_prep_w1p(const float* __restrict__ W1, unsigned short* __restrict__ W1P,
                           int total) {
    int t = blockIdx.x * blockDim.x + threadIdx.x;
    if (t >= total) return;
    int lane = t & 63;
    int r = t >> 6;
    int ks = r % KS1; r /= KS1;
    int nf = r % 40;
    int l = r / 40;
    int n = nf * 16 + (lane & 15);
    int kb = ks * 32 + (lane >> 4) * 8;
    unsigned short v[8];
#pragma unroll
    for (int e = 0; e < 8; ++e) {
        int k = kb + e;
        v[e] = (n < HID && k < EMB) ? f2bf(W1[(size_t)l * EMB * HID + (size_t)k * HID + n]) : 0;
    }
    *(short8*)(W1P + (size_t)t * 8) = *(short8*)v;
}

// W2P[l][nf=0..19][ks=0..KS2-1][lane][8]: frag elem = W2[l][ks*32+(lane>>4)*8+e][nf*16+(lane&15)]
__global__ void k_prep_w2p(const float* __restrict__ W2, unsigned short* __restrict__ W2P,
                           int total) {
    int t = blockIdx.x * blockDim.x + threadIdx.x;
    if (t >= total) return;
    int lane = t & 63;
    int r = t >> 6;
    int ks = r % KS2; r /= KS2;
    int nf = r % 20;
    int l = r / 20;
    int n = nf * 16 + (lane & 15);
    int kb = ks * 32 + (lane >> 4) * 8;
    unsigned short v[8];
#pragma unroll
    for (int e = 0; e < 8; ++e) {
        int k = kb + e;
        v[e] = (n < EMB && k < HID) ? f2bf(W2[(size_t)l * HID * EMB + (size_t)k * EMB + n]) : 0;
    }
    *(short8*)(W2P + (size_t)t * 8) = *(short8*)v;
}

__global__ void k_prep_params(const float* __restrict__ b1, const float* __restrict__ b2,
                              const float* __restrict__ g, const float* __restrict__ be,
                              const float* __restrict__ mu, const float* __restrict__ va,
                              float* __restrict__ b1p, float* __restrict__ scp,
                              float* __restrict__ shp, int total) {
    int t = blockIdx.x * blockDim.x + threadIdx.x;
    if (t >= total) return;
    int n = t % HS, l = t / HS;
    b1p[t] = (n < HID) ? b1[l * HID + n] : 0.f;
    if (n < FS) {
        float sc = 0.f, sh = 0.f;
        if (n < EMB) {
            sc = g[l * EMB + n] * rsqrtf(va[l * EMB + n] + BN_EPS);
            sh = be[l * EMB + n] + (b2[l * EMB + n] - mu[l * EMB + n]) * sc;
        }
        scp[l * FS + n] = sc;
        shp[l * FS + n] = sh;
    }
}

// ---------------- aggregation: 8 nodes/wave, batched CSR via lane loads + shfl ----------------
__global__ __launch_bounds__(256)
void k_aggregate(const unsigned short* __restrict__ fb,
                 const float* __restrict__ e0, const float* __restrict__ e1,
                 const int* __restrict__ roff, const int* __restrict__ srcs,
                 const int* __restrict__ cnt9,
                 unsigned short* __restrict__ agg, int n) {
    const int v0 = (blockIdx.x * 4 + (threadIdx.x >> 6)) * NPW;
    if (v0 >= n) return;
    const int lane = threadIdx.x & 63;
    const int nv = min(NPW, n - v0);

    int rv = 0;
    {
        int idx = v0 + lane;
        if (lane <= NPW && idx <= n) rv = roff[idx];
    }
    const int base = __shfl(rv, 0);
    const int total = __shfl(rv, nv) - base;

    const int n9 = n * 9;
    const int base9 = v0 * 9;
    int c0 = (base9 + lane < n9) ? cnt9[base9 + lane] : 0;
    int c1 = (lane < 8 && base9 + 64 + lane < n9) ? cnt9[base9 + 64 + lane] : 0;

    int c = 0;
    int chunk = 0;
    auto nextIdx = [&]() -> int {
        if ((c & 63) == 0)
            chunk = (c + lane < total) ? srcs[base + c + lane] : 0;
        int r = __shfl(chunk, c & 63);
        ++c;
        return r;
    };

#pragma unroll
    for (int i = 0; i < NPW; ++i) {
        if (i < nv) {
            const int di = __shfl(rv, i + 1) - __shfl(rv, i);
            float aA[4] = {0.f, 0.f, 0.f, 0.f};
            float aB[4] = {0.f, 0.f, 0.f, 0.f};
            int k = 0;
            for (; k + 4 <= di; k += 4) {
                int i0 = nextIdx(), i1 = nextIdx(), i2 = nextIdx(), i3 = nextIdx();
                const us4* r0 = (const us4*)(fb + (size_t)i0 * FS);
                const us4* r1 = (const us4*)(fb + (size_t)i1 * FS);
                const us4* r2 = (const us4*)(fb + (size_t)i2 * FS);
                const us4* r3 = (const us4*)(fb + (size_t)i3 * FS);
                us4 x0 = r0[lane], x1 = r1[lane], x2 = r2[lane], x3 = r3[lane];
                us4 y0 = {}, y1 = {}, y2 = {}, y3 = {};
                if (lane < 11) { y0 = r0[64 + lane]; y1 = r1[64 + lane];
                                 y2 = r2[64 + lane]; y3 = r3[64 + lane]; }
#pragma unroll
                for (int q = 0; q < 4; ++q)
                    aA[q] += (bf2f(x0[q]) + bf2f(x1[q])) + (bf2f(x2[q]) + bf2f(x3[q]));
                if (lane < 11) {
#pragma unroll
                    for (int q = 0; q < 4; ++q)
                        aB[q] += (bf2f(y0[q]) + bf2f(y1[q])) + (bf2f(y2[q]) + bf2f(y3[q]));
                }
            }
            for (; k < di; ++k) {
                int i0 = nextIdx();
                const us4* r0 = (const us4*)(fb + (size_t)i0 * FS);
                us4 x0 = r0[lane];
#pragma unroll
                for (int q = 0; q < 4; ++q) aA[q] += bf2f(x0[q]);
                if (lane < 11) {
                    us4 y0 = r0[64 + lane];
#pragma unroll
                    for (int q = 0; q < 4; ++q) aB[q] += bf2f(y0[q]);
                }
            }
#pragma unroll
            for (int t = 0; t < 9; ++t) {
                const int pos = i * 9 + t;
                int cv = __shfl(pos < 64 ? c0 : c1, pos & 63);
                if (cv) {
                    float fc = (float)cv;
                    const float* row = (t < 6) ? (e0 + t * EMB) : (e1 + (t - 6) * EMB);
                    f32x4 ea = *(const f32x4*)(row + 4 * lane);
#pragma unroll
                    for (int q = 0; q < 4; ++q) aA[q] += fc * ea[q];
                    if (lane < 11) {
                        f32x4 eb = *(const f32x4*)(row + 256 + 4 * lane);
#pragma unroll
                        for (int q = 0; q < 4; ++q) aB[q] += fc * eb[q];
                    }
                }
            }
            us4* ar = (us4*)(agg + (size_t)(v0 + i) * FS);
            us4 h;
#pragma unroll
            for (int q = 0; q < 4; ++q) h[q] = f2bf(aA[q]);
            ar[lane] = h;
            if (lane < 11) {
                us4 hb;
#pragma unroll
                for (int q = 0; q < 4; ++q) hb[q] = f2bf(aB[q]);
                ar[64 + lane] = hb;
            }
        }
    }
}

// ---------------- fused MLP (asm-pinned prefetch, 2-ks phases) ----------------
// One block per 64-row strip; 512 threads (8 waves). A-strip + H in XOR-swizzled
// LDS. Weight fragments double-buffered in named register sets wA/wB (10 frags =
// 2 K-steps per set) via asm-volatile global_load_dwordx4; consumed under counted
// s_waitcnt vmcnt(10) + sched_barrier(0). Phase = 8 ds_read + 20 MFMA (~300 cy)
// so the 1-phase prefetch distance exceeds L2 latency. (512,2) for headroom.
// EPI 1: BN + relu; EPI 2: BN only (last layer).
template <int EPI>
__global__ __launch_bounds__(512, 2)
void k_mlp(const unsigned short* __restrict__ A,     // [M_pad][FS] bf16
           const unsigned short* __restrict__ W1P,   // [40][KS1][64][8]
           const unsigned short* __restrict__ W2P,   // [20][KS2][64][8]
           const float* __restrict__ b1p,            // [HS]
           const float* __restrict__ scp, const float* __restrict__ shp,  // [FS]
           unsigned short* __restrict__ Cout) {      // [M_pad][FS] bf16
    __shared__ unsigned short Ash[64 * 320];   // 40 KB, swizzled
    __shared__ unsigned short Hsh[64 * 640];   // 80 KB, swizzled
    const int tid = threadIdx.x;
    const int lane = tid & 63, wid = tid >> 6;
    const int lr = lane & 15, lk = lane >> 4, rgrp = lk * 4;
    const size_t m0s = (size_t)blockIdx.x * 64;
    const int swz = (lr & 7) << 4;

    // ---- stage A strip (swizzled) ----
#pragma unroll
    for (int cch = 0; cch < 5; ++cch) {
        const int sbase = wid * 5120 + cch * 1024;
        const int s = sbase + lane * 16;
        const int row = s / 640;
        const int u = s ^ ((row & 7) << 4);   // involution within the row
        GLDS16((const char*)A + m0s * 640 + u, (char*)Ash + sbase);
    }

    // ---- GEMM1 weight pointers + preload phase0 (ks 0,1) ----
    const unsigned short* p1[5];
#pragma unroll
    for (int i = 0; i < 5; ++i)
        p1[i] = W1P + (((size_t)(wid * 5 + i) * KS1) * 64 + lane) * 8;
    short8 wA0, wA1, wA2, wA3, wA4, wA5, wA6, wA7, wA8, wA9;
    short8 wB0, wB1, wB2, wB3, wB4, wB5, wB6, wB7, wB8, wB9;
    LSET(wA, p1, 0);

    asm volatile("s_waitcnt vmcnt(0)" ::: "memory");
    __builtin_amdgcn_sched_barrier(0);
    __syncthreads();

    // ---- GEMM1: H[64][640] = relu(A x W1 + b1); wave wid owns cols wid*80..+80 ----
    f32x4 acc1[5][4] = {};

#define G1_PH(W, KS)                                                           \
    do {                                                                       \
        short8 a[8];                                                           \
        _Pragma("unroll")                                                      \
        for (int j = 0; j < 4; ++j) {                                          \
            const int o0 = ((j * 16 + lr) * 640 + (KS) * 64 + lk * 16) ^ swz;  \
            const int o1 = ((j * 16 + lr) * 640 + ((KS) + 1) * 64 + lk * 16) ^ swz; \
            a[j] = *(const short8*)((const char*)Ash + o0);                    \
            a[4 + j] = *(const short8*)((const char*)Ash + o1);                \
        }                                                                      \
        __builtin_amdgcn_s_setprio(1);                                         \
        _Pragma("unroll")                                                      \
        for (int j = 0; j < 4; ++j) {                                          \
            MFMA(acc1[0][j], W##0, a[j]); MFMA(acc1[1][j], W##1, a[j]);        \
            MFMA(acc1[2][j], W##2, a[j]); MFMA(acc1[3][j], W##3, a[j]);        \
            MFMA(acc1[4][j], W##4, a[j]);                                      \
        }                                                                      \
        _Pragma("unroll")                                                      \
        for (int j = 0; j < 4; ++j) {                                          \
            MFMA(acc1[0][j], W##5, a[4 + j]); MFMA(acc1[1][j], W##6, a[4 + j]);\
            MFMA(acc1[2][j], W##7, a[4 + j]); MFMA(acc1[3][j], W##8, a[4 + j]);\
            MFMA(acc1[4][j], W##9, a[4 + j]);                                  \
        }                                                                      \
        __builtin_amdgcn_s_setprio(0);                                         \
    } while (0)

    LSET(wB, p1, 2); WAITK; G1_PH(wA, 0);
    LSET(wA, p1, 4); WAITK; G1_PH(wB, 2);
    LSET(wB, p1, 6); WAITK; G1_PH(wA, 4);
    LSET(wA, p1, 8); WAITK; G1_PH(wB, 6);
    WAIT0;                  G1_PH(wA, 8);

    // epilogue 1 -> Hsh (swizzled)
#pragma unroll
    for (int i = 0; i < 5; ++i) {
        const int n0 = wid * 80 + i * 16 + rgrp;
        const f32x4 q0 = *(const f32x4*)&b1p[n0];
#pragma unroll
        for (int j = 0; j < 4; ++j) {
            const int m = j * 16 + lr;
            us4 h;
#pragma unroll
            for (int p = 0; p < 4; ++p)
                h[p] = f2bf(fmaxf(acc1[i][j][p] + q0[p], 0.f));
            const int o = (m * 1280 + n0 * 2) ^ swz;
            *(us4*)((char*)Hsh + o) = h;
        }
    }

    // ---- GEMM2 weight pointers + preload phase0 (overlaps the barrier) ----
    const int wm2 = wid >> 2, wn2 = wid & 3;   // 2 x 4: 32 rows x 80 cols per wave
    const unsigned short* p2[5];
#pragma unroll
    for (int i = 0; i < 5; ++i)
        p2[i] = W2P + (((size_t)(wn2 * 5 + i) * KS2) * 64 + lane) * 8;
    LSET(wA, p2, 0);
    __syncthreads();

    // ---- GEMM2: F'[64][320] = BN(H[64][640] x W2); 2x4 grid ----
    {
        const int r0 = wm2 * 32 + lr;
        f32x4 acc2[5][2] = {};

#define G2_PH(W, KS)                                                           \
    do {                                                                       \
        const int o0 = (r0 * 1280 + (KS) * 64 + lk * 16) ^ swz;                \
        const int o1 = ((r0 + 16) * 1280 + (KS) * 64 + lk * 16) ^ swz;         \
        const int o2 = (r0 * 1280 + ((KS) + 1) * 64 + lk * 16) ^ swz;          \
        const int o3 = ((r0 + 16) * 1280 + ((KS) + 1) * 64 + lk * 16) ^ swz;   \
        short8 h0 = *(const short8*)((const char*)Hsh + o0);                   \
        short8 h1 = *(const short8*)((const char*)Hsh + o1);                   \
        short8 h2 = *(const short8*)((const char*)Hsh + o2);                   \
        short8 h3 = *(const short8*)((const char*)Hsh + o3);                   \
        __builtin_amdgcn_s_setprio(1);                                         \
        MFMA(acc2[0][0], W##0, h0); MFMA(acc2[0][1], W##0, h1);                \
        MFMA(acc2[1][0], W##1, h0); MFMA(acc2[1][1], W##1, h1);                \
        MFMA(acc2[2][0], W##2, h0); MFMA(acc2[2][1], W##2, h1);                \
        MFMA(acc2[3][0], W##3, h0); MFMA(acc2[3][1], W##3, h1);                \
        MFMA(acc2[4][0], W##4, h0); MFMA(acc2[4][1], W##4, h1);                \
        MFMA(acc2[0][0], W##5, h2); MFMA(acc2[0][1], W##5, h3);                \
        MFMA(acc2[1][0], W##6, h2); MFMA(acc2[1][1], W##6, h3);                \
        MFMA(acc2[2][0], W##7, h2); MFMA(acc2[2][1], W##7, h3);                \
        MFMA(acc2[3][0], W##8, h2); MFMA(acc2[3][1], W##8, h3);                \
        MFMA(acc2[4][0], W##9, h2); MFMA(acc2[4][1], W##9, h3);                \
        __builtin_amdgcn_s_setprio(0);                                         \
    } while (0)

        LSET(wB, p2, 2);  WAITK; G2_PH(wA, 0);
        LSET(wA, p2, 4);  WAITK; G2_PH(wB, 2);
        LSET(wB, p2, 6);  WAITK; G2_PH(wA, 4);
        LSET(wA, p2, 8);  WAITK; G2_PH(wB, 6);
        LSET(wB, p2, 10); WAITK; G2_PH(wA, 8);
        LSET(wA, p2, 12); WAITK; G2_PH(wB, 10);
        LSET(wB, p2, 14); WAITK; G2_PH(wA, 12);
        LSET(wA, p2, 16); WAITK; G2_PH(wB, 14);
        LSET(wB, p2, 18); WAITK; G2_PH(wA, 16);
        WAIT0;                   G2_PH(wB, 18);

        // epilogue 2 -> global
#pragma unroll
        for (int i = 0; i < 5; ++i) {
            const int n0 = wn2 * 80 + i * 16 + rgrp;    // < 320
            const f32x4 q0 = *(const f32x4*)&scp[n0];
            const f32x4 q1 = *(const f32x4*)&shp[n0];
#pragma unroll
            for (int j = 0; j < 2; ++j) {
                const size_t m = m0s + (size_t)(wm2 * 32 + j * 16 + lr);
                us4 h;
#pragma unroll
                for (int p = 0; p < 4; ++p) {
                    float x = acc2[i][j][p] * q0[p] + q1[p];
                    if (EPI == 1) x = fmaxf(x, 0.f);
                    h[p] = f2bf(x);
                }
                *(us4*)(Cout + m * FS + n0) = h;
            }
        }
    }
}

// ---------------- per-graph pooling: one block (4 waves) per graph ----------------
__global__ __launch_bounds__(256)
void k_pool(const unsigned short* __restrict__ feats, const int* __restrict__ gstart,
            float* __restrict__ out, int l) {
    const int g = blockIdx.x;
    const int tid = threadIdx.x;
    const int w = tid >> 6, lane = tid & 63;
    const int s = gstart[g], e = gstart[g + 1];
    float aA[4] = {0.f, 0.f, 0.f, 0.f};
    float aB[4] = {0.f, 0.f, 0.f, 0.f};
    int v = s + w;
    for (; v + 4 < e; v += 8) {
        const us4* r0 = (const us4*)(feats + (size_t)v * FS);
        const us4* r1 = (const us4*)(feats + (size_t)(v + 4) * FS);
        us4 x0 = r0[lane], x1 = r1[lane];
        us4 y0 = {}, y1 = {};
        if (lane < 11) { y0 = r0[64 + lane]; y1 = r1[64 + lane]; }
#pragma unroll
        for (int q = 0; q < 4; ++q) aA[q] += bf2f(x0[q]) + bf2f(x1[q]);
        if (lane < 11) {
#pragma unroll
            for (int q = 0; q < 4; ++q) aB[q] += bf2f(y0[q]) + bf2f(y1[q]);
        }
    }
    if (v < e) {
        const us4* r0 = (const us4*)(feats + (size_t)v * FS);
        us4 x0 = r0[lane];
#pragma unroll
        for (int q = 0; q < 4; ++q) aA[q] += bf2f(x0[q]);
        if (lane < 11) {
            us4 y0 = r0[64 + lane];
#pragma unroll
            for (int q = 0; q < 4; ++q) aB[q] += bf2f(y0[q]);
        }
    }
    __shared__ f32x4 smA[4][64];
    __shared__ f32x4 smB[4][16];
    f32x4 xa;
#pragma unroll
    for (int q = 0; q < 4; ++q) xa[q] = aA[q];
    smA[w][lane] = xa;
    if (lane < 16) {
        f32x4 xb;
#pragma unroll
        for (int q = 0; q < 4; ++q) xb[q] = aB[q];
        smB[w][lane] = xb;
    }
    __syncthreads();
    if (w == 0) {
        f32x4 t = smA[0][lane] + smA[1][lane] + smA[2][lane] + smA[3][lane];
        float inv = 1.0f / fmaxf((float)(e - s), 1.0f);
        float* oavg = out + (size_t)g * (12 * EMB) + l * EMB;
        float* osum = oavg + 6 * EMB;
        *(f32x4*)(oavg + 4 * lane) = t * inv;
        *(f32x4*)(osum + 4 * lane) = t;
        if (lane < 11) {
            f32x4 tb = smB[0][lane] + smB[1][lane] + smB[2][lane] + smB[3][lane];
            *(f32x4*)(oavg + 256 + 4 * lane) = tb * inv;
            *(f32x4*)(osum + 256 + 4 * lane) = tb;
        }
    }
}

extern "C" void kernel_launch(void* const* d_in, const int* in_sizes, int n_in,
                              void* d_out, int out_size, void* d_ws, size_t ws_size,
                              hipStream_t stream) {
    const int*   an  = (const int*)d_in[0];
    const int*   ch  = (const int*)d_in[1];
    const int*   bt  = (const int*)d_in[2];
    const int*   bd  = (const int*)d_in[3];
    const int*   src = (const int*)d_in[4];
    const int*   dst = (const int*)d_in[5];
    const int*   gid = (const int*)d_in[6];
    const float* ne0 = (const float*)d_in[8];
    const float* ne1 = (const float*)d_in[9];
    const float* ee0 = (const float*)d_in[10];
    const float* ee1 = (const float*)d_in[11];
    const float* W1  = (const float*)d_in[12];
    const float* b1  = (const float*)d_in[13];
    const float* W2  = (const float*)d_in[14];
    const float* b2  = (const float*)d_in[15];
    const float* bng = (const float*)d_in[16];
    const float* bnb = (const float*)d_in[17];
    const float* bnm = (const float*)d_in[18];
    const float* bnv = (const float*)d_in[19];

    const int N = in_sizes[0];
    const int E = in_sizes[2];
    const int G = out_size / (12 * EMB);
    const int M_pad = ((N + 63) / 64) * 64;
    const int MT = M_pad / 64;
    const int nb = (N + 1023) / 1024;

    char* ws = (char*)d_ws;
    size_t off = 0;
    auto alloc = [&](size_t bytes) -> void* {
        void* p = (void*)(ws + off);
        off += (bytes + 255) & ~(size_t)255;
        return p;
    };
    unsigned short* Fb0  = (unsigned short*)alloc((size_t)M_pad * FS * 2);  // bf16 feats ping
    unsigned short* Fb1  = (unsigned short*)alloc((size_t)M_pad * FS * 2);  // bf16 feats pong
    unsigned short* A1   = (unsigned short*)alloc((size_t)M_pad * FS * 2);  // agg (MLP input)
    unsigned short* W1P  = (unsigned short*)alloc((size_t)NL * 40 * KS1 * 64 * 8 * 2);
    unsigned short* W2P  = (unsigned short*)alloc((size_t)NL * 20 * KS2 * 64 * 8 * 2);
    float*          b1p  = (float*)alloc((size_t)NL * HS * 4);
    float*          scp  = (float*)alloc((size_t)NL * FS * 4);
    float*          shp  = (float*)alloc((size_t)NL * FS * 4);
    int*            deg  = (int*)alloc((size_t)N * 4);
    int*            roff = (int*)alloc(((size_t)N + 1) * 4);
    int*            curs = (int*)alloc((size_t)N * 4);
    int*            srcs = (int*)alloc((size_t)E * 4);
    int*            cnt9 = (int*)alloc((size_t)N * 9 * 4);
    int*            incl = (int*)alloc((size_t)N * 4);
    int*            part = (int*)alloc((size_t)1024 * 4);
    int*            gst  = (int*)alloc(((size_t)G + 1) * 4);

    // weight / param prep (fragment-packed)
    {
        int t1 = NL * 40 * KS1 * 64;
        k_prep_w1p<<<(t1 + 255) / 256, 256, 0, stream>>>(W1, W1P, t1);
        int t2 = NL * 20 * KS2 * 64;
        k_prep_w2p<<<(t2 + 255) / 256, 256, 0, stream>>>(W2, W2P, t2);
        int t3 = NL * HS;
        k_prep_params<<<(t3 + 255) / 256, 256, 0, stream>>>(b1, b2, bng, bnb, bnm, bnv,
                                                            b1p, scp, shp, t3);
    }

    // h0 (bf16)
    {
        int tt = N * (FS / 4);
        k_init_h0<<<(tt + 255) / 256, 256, 0, stream>>>(an, ch, ne0, ne1, Fb0, N);
    }

    // CSR by dst + categorical counts (hierarchical scan) + graph bounds
    hipMemsetAsync(deg, 0, (size_t)N * 4, stream);
    hipMemsetAsync(cnt9, 0, (size_t)N * 9 * 4, stream);
    k_hist<<<(E + 255) / 256, 256, 0, stream>>>(dst, bt, bd, deg, cnt9, E);
    k_scan_blk<<<nb, 256, 0, stream>>>(deg, incl, part, N);
    k_scan_part<<<1, 1024, 0, stream>>>(part, nb);
    k_scan_add<<<(N + 255) / 256, 256, 0, stream>>>(incl, part, deg, roff, curs, N);
    k_scatter<<<(E + 255) / 256, 256, 0, stream>>>(dst, src, curs, srcs, E);
    k_gbound<<<(N + 255) / 256, 256, 0, stream>>>(gid, gst, N, G);

    const int aggBlocks = (N + 4 * NPW - 1) / (4 * NPW);

    unsigned short* Fbc = Fb0;
    unsigned short* Fbo = Fb1;
    for (int l = 0; l < NL; ++l) {
        k_pool<<<G, 256, 0, stream>>>(Fbc, gst, (float*)d_out, l);
        k_aggregate<<<aggBlocks, 256, 0, stream>>>(Fbc,
                                                   ee0 + (size_t)l * 6 * EMB,
                                                   ee1 + (size_t)l * 3 * EMB,
                                                   roff, srcs, cnt9, A1, N);
        const unsigned short* W1Pl = W1P + (size_t)l * 40 * KS1 * 64 * 8;
        const unsigned short* W2Pl = W2P + (size_t)l * 20 * KS2 * 64 * 8;
        if (l < NL - 1)
            k_mlp<1><<<MT, 512, 0, stream>>>(A1, W1Pl, W2Pl,
                                             b1p + (size_t)l * HS,
                                             scp + (size_t)l * FS, shp + (size_t)l * FS,
                                             Fbo);
        else
            k_mlp<2><<<MT, 512, 0, stream>>>(A1, W1Pl, W2Pl,
                                             b1p + (size_t)l * HS,
                                             scp + (size_t)l * FS, shp + (size_t)l * FS,
                                             Fbo);
        unsigned short* t = Fbc; Fbc = Fbo; Fbo = t;
    }
    k_pool<<<G, 256, 0, stream>>>(Fbc, gst, (float*)d_out, NL);
}

// Round 17
// 690.162 us; speedup vs baseline: 1.0119x; 1.0119x over previous
//
#include <hip/hip_runtime.h>

#define EMB 300
#define HID 600
#define NL 5
#define BN_EPS 1e-5f

#define FS 320          // padded feature stride (300 -> 320); row = 640 B
#define HS 640          // padded hidden stride (600 -> 640)
#define NPW 8           // nodes per wave in k_aggregate
#define KS1 10          // GEMM1 K-steps (320/32)
#define KS2 20          // GEMM2 K-steps (640/32)

typedef __attribute__((ext_vector_type(8))) short short8;
typedef __attribute__((ext_vector_type(4))) float f32x4;
typedef __attribute__((ext_vector_type(4))) unsigned short us4;

__device__ __forceinline__ unsigned short f2bf(float x) {
    unsigned u = __float_as_uint(x);
    unsigned r = (u + 0x7FFFu + ((u >> 16) & 1u)) >> 16;   // RNE
    return (unsigned short)r;
}
__device__ __forceinline__ float bf2f(unsigned short h) {
    return __uint_as_float(((unsigned)h) << 16);
}

#define GLDS16(gsrc, ldst)                                                     \
    __builtin_amdgcn_global_load_lds(                                          \
        (const __attribute__((address_space(1))) unsigned int*)(gsrc),         \
        (__attribute__((address_space(3))) unsigned int*)(ldst), 16, 0, 0)

// pinned-issue 16B weight load (prefetch the compiler refuses to schedule)
#define GLOAD8(dst, ptr)                                                       \
    asm volatile("global_load_dwordx4 %0, %1, off" : "=v"(dst) : "v"(ptr))

// ---------------- h0 = node_emb0[an] + node_emb1[ch] -> bf16, stride FS ----------------
__global__ void k_init_h0(const int* __restrict__ an, const int* __restrict__ ch,
                          const float* __restrict__ ne0, const float* __restrict__ ne1,
                          unsigned short* __restrict__ Fb, int n) {
    int t = blockIdx.x * blockDim.x + threadIdx.x;
    int i = t / (FS / 4), f4 = t - i * (FS / 4);
    if (i >= n) return;
    int f = f4 * 4;
    us4 h = {0, 0, 0, 0};
    if (f < EMB) {  // EMB=300 is a multiple of 4; rows are 16B-aligned
        const float4 a = *(const float4*)(ne0 + (size_t)an[i] * EMB + f);
        const float4 b = *(const float4*)(ne1 + (size_t)ch[i] * EMB + f);
        h[0] = f2bf(a.x + b.x); h[1] = f2bf(a.y + b.y);
        h[2] = f2bf(a.z + b.z); h[3] = f2bf(a.w + b.w);
    }
    *(us4*)(Fb + (size_t)i * FS + f) = h;
}

// ---------------- CSR build (by dst) + per-node categorical counts [N][9] ----------------
__global__ void k_hist(const int* __restrict__ dst, const int* __restrict__ bt,
                       const int* __restrict__ bd, int* __restrict__ deg,
                       int* __restrict__ cnt9, int e) {
    int t = blockIdx.x * blockDim.x + threadIdx.x;
    if (t >= e) return;
    int d = dst[t];
    atomicAdd(&deg[d], 1);
    atomicAdd(&cnt9[d * 9 + bt[t]], 1);
    atomicAdd(&cnt9[d * 9 + 6 + bd[t]], 1);
}

// ---- hierarchical scan: pass A ----
__global__ __launch_bounds__(256)
void k_scan_blk(const int* __restrict__ deg, int* __restrict__ incl,
                int* __restrict__ part, int n) {
    int tid = threadIdx.x;
    int base = blockIdx.x * 1024 + tid * 4;
    int v0 = (base + 0 < n) ? deg[base + 0] : 0;
    int v1 = (base + 1 < n) ? deg[base + 1] : 0;
    int v2 = (base + 2 < n) ? deg[base + 2] : 0;
    int v3 = (base + 3 < n) ? deg[base + 3] : 0;
    int ts = v0 + v1 + v2 + v3;
    int lane = tid & 63, w = tid >> 6;
    int x = ts;
#pragma unroll
    for (int off = 1; off < 64; off <<= 1) {
        int y = __shfl_up(x, off);
        if (lane >= off) x += y;
    }
    __shared__ int ws[4];
    if (lane == 63) ws[w] = x;
    __syncthreads();
    int woff = 0;
    for (int i = 0; i < w; ++i) woff += ws[i];
    int r = woff + x - ts;
    r += v0; if (base + 0 < n) incl[base + 0] = r;
    r += v1; if (base + 1 < n) incl[base + 1] = r;
    r += v2; if (base + 2 < n) incl[base + 2] = r;
    r += v3; if (base + 3 < n) incl[base + 3] = r;
    if (tid == 255) part[blockIdx.x] = woff + x;
}

// ---- pass B ----
__global__ __launch_bounds__(1024)
void k_scan_part(int* __restrict__ part, int nb) {
    int tid = threadIdx.x;
    int v = (tid < nb) ? part[tid] : 0;
    int lane = tid & 63, w = tid >> 6;
    int x = v;
#pragma unroll
    for (int off = 1; off < 64; off <<= 1) {
        int y = __shfl_up(x, off);
        if (lane >= off) x += y;
    }
    __shared__ int ws[16];
    if (lane == 63) ws[w] = x;
    __syncthreads();
    int woff = 0;
    for (int i = 0; i < w; ++i) woff += ws[i];
    if (tid < nb) part[tid] = woff + x - v;
}

// ---- pass C ----
__global__ void k_scan_add(const int* __restrict__ incl, const int* __restrict__ part,
                           const int* __restrict__ deg, int* __restrict__ roff,
                           int* __restrict__ curs, int n) {
    int i = blockIdx.x * blockDim.x + threadIdx.x;
    if (i >= n) return;
    int inc = incl[i] + part[i >> 10];
    roff[i + 1] = inc;
    curs[i] = inc - deg[i];
    if (i == 0) roff[0] = 0;
}

__global__ void k_scatter(const int* __restrict__ dst, const int* __restrict__ src,
                          int* __restrict__ cursor, int* __restrict__ srcs, int e) {
    int t = blockIdx.x * blockDim.x + threadIdx.x;
    if (t < e) { int p = atomicAdd(&cursor[dst[t]], 1); srcs[p] = src[t]; }
}

// ---- graph boundaries ----
__global__ void k_gbound(const int* __restrict__ gids, int* __restrict__ gstart,
                         int n, int G) {
    int i = blockIdx.x * blockDim.x + threadIdx.x;
    if (i >= n) return;
    int g = gids[i];
    int gp = (i == 0) ? -1 : gids[i - 1];
    for (int q = gp + 1; q <= g; ++q) gstart[q] = i;
    if (i == n - 1)
        for (int q = g + 1; q <= G; ++q) gstart[q] = n;
}

// ---------------- weight prep: MFMA-fragment-packed bf16 weights ----------------
// W1P[l][nf=0..39][ks=0..KS1-1][lane][8]: frag elem = W1[l][ks*32+(lane>>4)*8+e][nf*16+(lane&15)]
__global__ void k_prep_w1p(const float* __restrict__ W1, unsigned short* __restrict__ W1P,
                           int total) {
    int t = blockIdx.x * blockDim.x + threadIdx.x;
    if (t >= total) return;
    int lane = t & 63;
    int r = t >> 6;
    int ks = r % KS1; r /= KS1;
    int nf = r % 40;
    int l = r / 40;
    int n = nf * 16 + (lane & 15);
    int kb = ks * 32 + (lane >> 4) * 8;
    unsigned short v[8];
#pragma unroll
    for (int e = 0; e < 8; ++e) {
        int k = kb + e;
        v[e] = (n < HID && k < EMB) ? f2bf(W1[(size_t)l * EMB * HID + (size_t)k * HID + n]) : 0;
    }
    *(short8*)(W1P + (size_t)t * 8) = *(short8*)v;
}

// W2P[l][nf=0..19][ks=0..KS2-1][lane][8]: frag elem = W2[l][ks*32+(lane>>4)*8+e][nf*16+(lane&15)]
__global__ void k_prep_w2p(const float* __restrict__ W2, unsigned short* __restrict__ W2P,
                           int total) {
    int t = blockIdx.x * blockDim.x + threadIdx.x;
    if (t >= total) return;
    int lane = t & 63;
    int r = t >> 6;
    int ks = r % KS2; r /= KS2;
    int nf = r % 20;
    int l = r / 20;
    int n = nf * 16 + (lane & 15);
    int kb = ks * 32 + (lane >> 4) * 8;
    unsigned short v[8];
#pragma unroll
    for (int e = 0; e < 8; ++e) {
        int k = kb + e;
        v[e] = (n < EMB && k < HID) ? f2bf(W2[(size_t)l * HID * EMB + (size_t)k * EMB + n]) : 0;
    }
    *(short8*)(W2P + (size_t)t * 8) = *(short8*)v;
}

__global__ void k_prep_params(const float* __restrict__ b1, const float* __restrict__ b2,
                              const float* __restrict__ g, const float* __restrict__ be,
                              const float* __restrict__ mu, const float* __restrict__ va,
                              float* __restrict__ b1p, float* __restrict__ scp,
                              float* __restrict__ shp, int total) {
    int t = blockIdx.x * blockDim.x + threadIdx.x;
    if (t >= total) return;
    int n = t % HS, l = t / HS;
    b1p[t] = (n < HID) ? b1[l * HID + n] : 0.f;
    if (n < FS) {
        float sc = 0.f, sh = 0.f;
        if (n < EMB) {
            sc = g[l * EMB + n] * rsqrtf(va[l * EMB + n] + BN_EPS);
            sh = be[l * EMB + n] + (b2[l * EMB + n] - mu[l * EMB + n]) * sc;
        }
        scp[l * FS + n] = sc;
        shp[l * FS + n] = sh;
    }
}

// ---------------- aggregation: 8 nodes/wave, batched CSR via lane loads + shfl ----------------
__global__ __launch_bounds__(256)
void k_aggregate(const unsigned short* __restrict__ fb,
                 const float* __restrict__ e0, const float* __restrict__ e1,
                 const int* __restrict__ roff, const int* __restrict__ srcs,
                 const int* __restrict__ cnt9,
                 unsigned short* __restrict__ agg, int n) {
    const int v0 = (blockIdx.x * 4 + (threadIdx.x >> 6)) * NPW;
    if (v0 >= n) return;
    const int lane = threadIdx.x & 63;
    const int nv = min(NPW, n - v0);

    int rv = 0;
    {
        int idx = v0 + lane;
        if (lane <= NPW && idx <= n) rv = roff[idx];
    }
    const int base = __shfl(rv, 0);
    const int total = __shfl(rv, nv) - base;

    const int n9 = n * 9;
    const int base9 = v0 * 9;
    int c0 = (base9 + lane < n9) ? cnt9[base9 + lane] : 0;
    int c1 = (lane < 8 && base9 + 64 + lane < n9) ? cnt9[base9 + 64 + lane] : 0;

    int c = 0;
    int chunk = 0;
    auto nextIdx = [&]() -> int {
        if ((c & 63) == 0)
            chunk = (c + lane < total) ? srcs[base + c + lane] : 0;
        int r = __shfl(chunk, c & 63);
        ++c;
        return r;
    };

#pragma unroll
    for (int i = 0; i < NPW; ++i) {
        if (i < nv) {
            const int di = __shfl(rv, i + 1) - __shfl(rv, i);
            float aA[4] = {0.f, 0.f, 0.f, 0.f};
            float aB[4] = {0.f, 0.f, 0.f, 0.f};
            int k = 0;
            for (; k + 4 <= di; k += 4) {
                int i0 = nextIdx(), i1 = nextIdx(), i2 = nextIdx(), i3 = nextIdx();
                const us4* r0 = (const us4*)(fb + (size_t)i0 * FS);
                const us4* r1 = (const us4*)(fb + (size_t)i1 * FS);
                const us4* r2 = (const us4*)(fb + (size_t)i2 * FS);
                const us4* r3 = (const us4*)(fb + (size_t)i3 * FS);
                us4 x0 = r0[lane], x1 = r1[lane], x2 = r2[lane], x3 = r3[lane];
                us4 y0 = {}, y1 = {}, y2 = {}, y3 = {};
                if (lane < 11) { y0 = r0[64 + lane]; y1 = r1[64 + lane];
                                 y2 = r2[64 + lane]; y3 = r3[64 + lane]; }
#pragma unroll
                for (int q = 0; q < 4; ++q)
                    aA[q] += (bf2f(x0[q]) + bf2f(x1[q])) + (bf2f(x2[q]) + bf2f(x3[q]));
                if (lane < 11) {
#pragma unroll
                    for (int q = 0; q < 4; ++q)
                        aB[q] += (bf2f(y0[q]) + bf2f(y1[q])) + (bf2f(y2[q]) + bf2f(y3[q]));
                }
            }
            for (; k < di; ++k) {
                int i0 = nextIdx();
                const us4* r0 = (const us4*)(fb + (size_t)i0 * FS);
                us4 x0 = r0[lane];
#pragma unroll
                for (int q = 0; q < 4; ++q) aA[q] += bf2f(x0[q]);
                if (lane < 11) {
                    us4 y0 = r0[64 + lane];
#pragma unroll
                    for (int q = 0; q < 4; ++q) aB[q] += bf2f(y0[q]);
                }
            }
#pragma unroll
            for (int t = 0; t < 9; ++t) {
                const int pos = i * 9 + t;
                int cv = __shfl(pos < 64 ? c0 : c1, pos & 63);
                if (cv) {
                    float fc = (float)cv;
                    const float* row = (t < 6) ? (e0 + t * EMB) : (e1 + (t - 6) * EMB);
                    f32x4 ea = *(const f32x4*)(row + 4 * lane);
#pragma unroll
                    for (int q = 0; q < 4; ++q) aA[q] += fc * ea[q];
                    if (lane < 11) {
                        f32x4 eb = *(const f32x4*)(row + 256 + 4 * lane);
#pragma unroll
                        for (int q = 0; q < 4; ++q) aB[q] += fc * eb[q];
                    }
                }
            }
            us4* ar = (us4*)(agg + (size_t)(v0 + i) * FS);
            us4 h;
#pragma unroll
            for (int q = 0; q < 4; ++q) h[q] = f2bf(aA[q]);
            ar[lane] = h;
            if (lane < 11) {
                us4 hb;
#pragma unroll
                for (int q = 0; q < 4; ++q) hb[q] = f2bf(aB[q]);
                ar[64 + lane] = hb;
            }
        }
    }
}

// ---------------- fused MLP (R11 structure + asm-pinned weight prefetch) ----------------
// One block per 64-row strip; 512 threads (8 waves). A-strip + H in XOR-swizzled
// LDS. Weight fragments double-buffered in named register sets wA/wB via
// asm-volatile global_load_dwordx4 (issue order pinned), consumed under counted
// s_waitcnt vmcnt(5) + sched_barrier(0). (512,2) for register headroom.
// EPI 1: BN + relu; EPI 2: BN only (last layer).
template <int EPI>
__global__ __launch_bounds__(512, 2)
void k_mlp(const unsigned short* __restrict__ A,     // [M_pad][FS] bf16
           const unsigned short* __restrict__ W1P,   // [40][KS1][64][8]
           const unsigned short* __restrict__ W2P,   // [20][KS2][64][8]
           const float* __restrict__ b1p,            // [HS]
           const float* __restrict__ scp, const float* __restrict__ shp,  // [FS]
           unsigned short* __restrict__ Cout) {      // [M_pad][FS] bf16
    __shared__ unsigned short Ash[64 * 320];   // 40 KB, swizzled
    __shared__ unsigned short Hsh[64 * 640];   // 80 KB, swizzled
    const int tid = threadIdx.x;
    const int lane = tid & 63, wid = tid >> 6;
    const int lr = lane & 15, lk = lane >> 4, rgrp = lk * 4;
    const size_t m0s = (size_t)blockIdx.x * 64;
    const int swz = (lr & 7) << 4;

    // ---- stage A strip (swizzled) ----
#pragma unroll
    for (int cch = 0; cch < 5; ++cch) {
        const int sbase = wid * 5120 + cch * 1024;
        const int s = sbase + lane * 16;
        const int row = s / 640;
        const int u = s ^ ((row & 7) << 4);   // involution within the row
        GLDS16((const char*)A + m0s * 640 + u, (char*)Ash + sbase);
    }

    // ---- GEMM1 weight pointers + preload ks=0 (overlaps A-stage drain) ----
    const unsigned short* p1[5];
#pragma unroll
    for (int i = 0; i < 5; ++i)
        p1[i] = W1P + (((size_t)(wid * 5 + i) * KS1) * 64 + lane) * 8;
    short8 wA0, wA1, wA2, wA3, wA4, wB0, wB1, wB2, wB3, wB4;
    GLOAD8(wA0, p1[0]); GLOAD8(wA1, p1[1]); GLOAD8(wA2, p1[2]);
    GLOAD8(wA3, p1[3]); GLOAD8(wA4, p1[4]);

    asm volatile("s_waitcnt vmcnt(0)" ::: "memory");
    __builtin_amdgcn_sched_barrier(0);
    __syncthreads();

    // ---- GEMM1: H[64][640] = relu(A x W1 + b1); wave wid owns cols wid*80..+80 ----
    f32x4 acc1[5][4] = {};
    {
#pragma unroll
        for (int kk = 0; kk < 5; ++kk) {
            {   // even ks = 2kk; prefetch ks+1 into wB
                const int ks = 2 * kk;
                GLOAD8(wB0, p1[0] + (ks + 1) * 512); GLOAD8(wB1, p1[1] + (ks + 1) * 512);
                GLOAD8(wB2, p1[2] + (ks + 1) * 512); GLOAD8(wB3, p1[3] + (ks + 1) * 512);
                GLOAD8(wB4, p1[4] + (ks + 1) * 512);
                asm volatile("s_waitcnt vmcnt(5)" ::: "memory");
                __builtin_amdgcn_sched_barrier(0);
                short8 a[4];
#pragma unroll
                for (int j = 0; j < 4; ++j) {
                    const int o = ((j * 16 + lr) * 640 + ks * 64 + lk * 16) ^ swz;
                    a[j] = *(const short8*)((const char*)Ash + o);
                }
                __builtin_amdgcn_s_setprio(1);
#pragma unroll
                for (int j = 0; j < 4; ++j) {
                    acc1[0][j] = __builtin_amdgcn_mfma_f32_16x16x32_bf16(wA0, a[j], acc1[0][j], 0, 0, 0);
                    acc1[1][j] = __builtin_amdgcn_mfma_f32_16x16x32_bf16(wA1, a[j], acc1[1][j], 0, 0, 0);
                    acc1[2][j] = __builtin_amdgcn_mfma_f32_16x16x32_bf16(wA2, a[j], acc1[2][j], 0, 0, 0);
                    acc1[3][j] = __builtin_amdgcn_mfma_f32_16x16x32_bf16(wA3, a[j], acc1[3][j], 0, 0, 0);
                    acc1[4][j] = __builtin_amdgcn_mfma_f32_16x16x32_bf16(wA4, a[j], acc1[4][j], 0, 0, 0);
                }
                __builtin_amdgcn_s_setprio(0);
            }
            {   // odd ks = 2kk+1; prefetch ks+1 into wA (unless done)
                const int ks = 2 * kk + 1;
                if (ks + 1 < KS1) {
                    GLOAD8(wA0, p1[0] + (ks + 1) * 512); GLOAD8(wA1, p1[1] + (ks + 1) * 512);
                    GLOAD8(wA2, p1[2] + (ks + 1) * 512); GLOAD8(wA3, p1[3] + (ks + 1) * 512);
                    GLOAD8(wA4, p1[4] + (ks + 1) * 512);
                    asm volatile("s_waitcnt vmcnt(5)" ::: "memory");
                } else {
                    asm volatile("s_waitcnt vmcnt(0)" ::: "memory");
                }
                __builtin_amdgcn_sched_barrier(0);
                short8 a[4];
#pragma unroll
                for (int j = 0; j < 4; ++j) {
                    const int o = ((j * 16 + lr) * 640 + ks * 64 + lk * 16) ^ swz;
                    a[j] = *(const short8*)((const char*)Ash + o);
                }
                __builtin_amdgcn_s_setprio(1);
#pragma unroll
                for (int j = 0; j < 4; ++j) {
                    acc1[0][j] = __builtin_amdgcn_mfma_f32_16x16x32_bf16(wB0, a[j], acc1[0][j], 0, 0, 0);
                    acc1[1][j] = __builtin_amdgcn_mfma_f32_16x16x32_bf16(wB1, a[j], acc1[1][j], 0, 0, 0);
                    acc1[2][j] = __builtin_amdgcn_mfma_f32_16x16x32_bf16(wB2, a[j], acc1[2][j], 0, 0, 0);
                    acc1[3][j] = __builtin_amdgcn_mfma_f32_16x16x32_bf16(wB3, a[j], acc1[3][j], 0, 0, 0);
                    acc1[4][j] = __builtin_amdgcn_mfma_f32_16x16x32_bf16(wB4, a[j], acc1[4][j], 0, 0, 0);
                }
                __builtin_amdgcn_s_setprio(0);
            }
        }
    }

    // epilogue 1 -> Hsh (swizzled)
#pragma unroll
    for (int i = 0; i < 5; ++i) {
        const int n0 = wid * 80 + i * 16 + rgrp;
        const f32x4 q0 = *(const f32x4*)&b1p[n0];
#pragma unroll
        for (int j = 0; j < 4; ++j) {
            const int m = j * 16 + lr;
            us4 h;
#pragma unroll
            for (int p = 0; p < 4; ++p)
                h[p] = f2bf(fmaxf(acc1[i][j][p] + q0[p], 0.f));
            const int o = (m * 1280 + n0 * 2) ^ swz;
            *(us4*)((char*)Hsh + o) = h;
        }
    }

    // ---- GEMM2 weight pointers + preload ks=0 (overlaps the barrier) ----
    const int wm2 = wid >> 2, wn2 = wid & 3;   // 2 x 4: 32 rows x 80 cols per wave
    const unsigned short* p2[5];
#pragma unroll
    for (int i = 0; i < 5; ++i)
        p2[i] = W2P + (((size_t)(wn2 * 5 + i) * KS2) * 64 + lane) * 8;
    GLOAD8(wA0, p2[0]); GLOAD8(wA1, p2[1]); GLOAD8(wA2, p2[2]);
    GLOAD8(wA3, p2[3]); GLOAD8(wA4, p2[4]);
    __syncthreads();

    // ---- GEMM2: F'[64][320] = BN(H[64][640] x W2); 2x4 grid ----
    {
        const int r0 = wm2 * 32 + lr;
        f32x4 acc2[5][2] = {};
#pragma unroll
        for (int kk = 0; kk < 10; ++kk) {
            {   // even ks = 2kk; prefetch ks+1 into wB
                const int ks = 2 * kk;
                GLOAD8(wB0, p2[0] + (ks + 1) * 512); GLOAD8(wB1, p2[1] + (ks + 1) * 512);
                GLOAD8(wB2, p2[2] + (ks + 1) * 512); GLOAD8(wB3, p2[3] + (ks + 1) * 512);
                GLOAD8(wB4, p2[4] + (ks + 1) * 512);
                asm volatile("s_waitcnt vmcnt(5)" ::: "memory");
                __builtin_amdgcn_sched_barrier(0);
                const int oh0 = (r0 * 1280 + ks * 64 + lk * 16) ^ swz;
                const int oh1 = ((r0 + 16) * 1280 + ks * 64 + lk * 16) ^ swz;
                short8 h0 = *(const short8*)((const char*)Hsh + oh0);
                short8 h1 = *(const short8*)((const char*)Hsh + oh1);
                __builtin_amdgcn_s_setprio(1);
                acc2[0][0] = __builtin_amdgcn_mfma_f32_16x16x32_bf16(wA0, h0, acc2[0][0], 0, 0, 0);
                acc2[0][1] = __builtin_amdgcn_mfma_f32_16x16x32_bf16(wA0, h1, acc2[0][1], 0, 0, 0);
                acc2[1][0] = __builtin_amdgcn_mfma_f32_16x16x32_bf16(wA1, h0, acc2[1][0], 0, 0, 0);
                acc2[1][1] = __builtin_amdgcn_mfma_f32_16x16x32_bf16(wA1, h1, acc2[1][1], 0, 0, 0);
                acc2[2][0] = __builtin_amdgcn_mfma_f32_16x16x32_bf16(wA2, h0, acc2[2][0], 0, 0, 0);
                acc2[2][1] = __builtin_amdgcn_mfma_f32_16x16x32_bf16(wA2, h1, acc2[2][1], 0, 0, 0);
                acc2[3][0] = __builtin_amdgcn_mfma_f32_16x16x32_bf16(wA3, h0, acc2[3][0], 0, 0, 0);
                acc2[3][1] = __builtin_amdgcn_mfma_f32_16x16x32_bf16(wA3, h1, acc2[3][1], 0, 0, 0);
                acc2[4][0] = __builtin_amdgcn_mfma_f32_16x16x32_bf16(wA4, h0, acc2[4][0], 0, 0, 0);
                acc2[4][1] = __builtin_amdgcn_mfma_f32_16x16x32_bf16(wA4, h1, acc2[4][1], 0, 0, 0);
                __builtin_amdgcn_s_setprio(0);
            }
            {   // odd ks = 2kk+1; prefetch ks+1 into wA (unless done)
                const int ks = 2 * kk + 1;
                if (ks + 1 < KS2) {
                    GLOAD8(wA0, p2[0] + (ks + 1) * 512); GLOAD8(wA1, p2[1] + (ks + 1) * 512);
                    GLOAD8(wA2, p2[2] + (ks + 1) * 512); GLOAD8(wA3, p2[3] + (ks + 1) * 512);
                    GLOAD8(wA4, p2[4] + (ks + 1) * 512);
                    asm volatile("s_waitcnt vmcnt(5)" ::: "memory");
                } else {
                    asm volatile("s_waitcnt vmcnt(0)" ::: "memory");
                }
                __builtin_amdgcn_sched_barrier(0);
                const int oh0 = (r0 * 1280 + ks * 64 + lk * 16) ^ swz;
                const int oh1 = ((r0 + 16) * 1280 + ks * 64 + lk * 16) ^ swz;
                short8 h0 = *(const short8*)((const char*)Hsh + oh0);
                short8 h1 = *(const short8*)((const char*)Hsh + oh1);
                __builtin_amdgcn_s_setprio(1);
                acc2[0][0] = __builtin_amdgcn_mfma_f32_16x16x32_bf16(wB0, h0, acc2[0][0], 0, 0, 0);
                acc2[0][1] = __builtin_amdgcn_mfma_f32_16x16x32_bf16(wB0, h1, acc2[0][1], 0, 0, 0);
                acc2[1][0] = __builtin_amdgcn_mfma_f32_16x16x32_bf16(wB1, h0, acc2[1][0], 0, 0, 0);
                acc2[1][1] = __builtin_amdgcn_mfma_f32_16x16x32_bf16(wB1, h1, acc2[1][1], 0, 0, 0);
                acc2[2][0] = __builtin_amdgcn_mfma_f32_16x16x32_bf16(wB2, h0, acc2[2][0], 0, 0, 0);
                acc2[2][1] = __builtin_amdgcn_mfma_f32_16x16x32_bf16(wB2, h1, acc2[2][1], 0, 0, 0);
                acc2[3][0] = __builtin_amdgcn_mfma_f32_16x16x32_bf16(wB3, h0, acc2[3][0], 0, 0, 0);
                acc2[3][1] = __builtin_amdgcn_mfma_f32_16x16x32_bf16(wB3, h1, acc2[3][1], 0, 0, 0);
                acc2[4][0] = __builtin_amdgcn_mfma_f32_16x16x32_bf16(wB4, h0, acc2[4][0], 0, 0, 0);
                acc2[4][1] = __builtin_amdgcn_mfma_f32_16x16x32_bf16(wB4, h1, acc2[4][1], 0, 0, 0);
                __builtin_amdgcn_s_setprio(0);
            }
        }
        // epilogue 2 -> global
#pragma unroll
        for (int i = 0; i < 5; ++i) {
            const int n0 = wn2 * 80 + i * 16 + rgrp;    // < 320
            const f32x4 q0 = *(const f32x4*)&scp[n0];
            const f32x4 q1 = *(const f32x4*)&shp[n0];
#pragma unroll
            for (int j = 0; j < 2; ++j) {
                const size_t m = m0s + (size_t)(wm2 * 32 + j * 16 + lr);
                us4 h;
#pragma unroll
                for (int p = 0; p < 4; ++p) {
                    float x = acc2[i][j][p] * q0[p] + q1[p];
                    if (EPI == 1) x = fmaxf(x, 0.f);
                    h[p] = f2bf(x);
                }
                *(us4*)(Cout + m * FS + n0) = h;
            }
        }
    }
}

// ---------------- per-graph pooling: one block (4 waves) per graph ----------------
__global__ __launch_bounds__(256)
void k_pool(const unsigned short* __restrict__ feats, const int* __restrict__ gstart,
            float* __restrict__ out, int l) {
    const int g = blockIdx.x;
    const int tid = threadIdx.x;
    const int w = tid >> 6, lane = tid & 63;
    const int s = gstart[g], e = gstart[g + 1];
    float aA[4] = {0.f, 0.f, 0.f, 0.f};
    float aB[4] = {0.f, 0.f, 0.f, 0.f};
    int v = s + w;
    for (; v + 4 < e; v += 8) {
        const us4* r0 = (const us4*)(feats + (size_t)v * FS);
        const us4* r1 = (const us4*)(feats + (size_t)(v + 4) * FS);
        us4 x0 = r0[lane], x1 = r1[lane];
        us4 y0 = {}, y1 = {};
        if (lane < 11) { y0 = r0[64 + lane]; y1 = r1[64 + lane]; }
#pragma unroll
        for (int q = 0; q < 4; ++q) aA[q] += bf2f(x0[q]) + bf2f(x1[q]);
        if (lane < 11) {
#pragma unroll
            for (int q = 0; q < 4; ++q) aB[q] += bf2f(y0[q]) + bf2f(y1[q]);
        }
    }
    if (v < e) {
        const us4* r0 = (const us4*)(feats + (size_t)v * FS);
        us4 x0 = r0[lane];
#pragma unroll
        for (int q = 0; q < 4; ++q) aA[q] += bf2f(x0[q]);
        if (lane < 11) {
            us4 y0 = r0[64 + lane];
#pragma unroll
            for (int q = 0; q < 4; ++q) aB[q] += bf2f(y0[q]);
        }
    }
    __shared__ f32x4 smA[4][64];
    __shared__ f32x4 smB[4][16];
    f32x4 xa;
#pragma unroll
    for (int q = 0; q < 4; ++q) xa[q] = aA[q];
    smA[w][lane] = xa;
    if (lane < 16) {
        f32x4 xb;
#pragma unroll
        for (int q = 0; q < 4; ++q) xb[q] = aB[q];
        smB[w][lane] = xb;
    }
    __syncthreads();
    if (w == 0) {
        f32x4 t = smA[0][lane] + smA[1][lane] + smA[2][lane] + smA[3][lane];
        float inv = 1.0f / fmaxf((float)(e - s), 1.0f);
        float* oavg = out + (size_t)g * (12 * EMB) + l * EMB;
        float* osum = oavg + 6 * EMB;
        *(f32x4*)(oavg + 4 * lane) = t * inv;
        *(f32x4*)(osum + 4 * lane) = t;
        if (lane < 11) {
            f32x4 tb = smB[0][lane] + smB[1][lane] + smB[2][lane] + smB[3][lane];
            *(f32x4*)(oavg + 256 + 4 * lane) = tb * inv;
            *(f32x4*)(osum + 256 + 4 * lane) = tb;
        }
    }
}

extern "C" void kernel_launch(void* const* d_in, const int* in_sizes, int n_in,
                              void* d_out, int out_size, void* d_ws, size_t ws_size,
                              hipStream_t stream) {
    const int*   an  = (const int*)d_in[0];
    const int*   ch  = (const int*)d_in[1];
    const int*   bt  = (const int*)d_in[2];
    const int*   bd  = (const int*)d_in[3];
    const int*   src = (const int*)d_in[4];
    const int*   dst = (const int*)d_in[5];
    const int*   gid = (const int*)d_in[6];
    const float* ne0 = (const float*)d_in[8];
    const float* ne1 = (const float*)d_in[9];
    const float* ee0 = (const float*)d_in[10];
    const float* ee1 = (const float*)d_in[11];
    const float* W1  = (const float*)d_in[12];
    const float* b1  = (const float*)d_in[13];
    const float* W2  = (const float*)d_in[14];
    const float* b2  = (const float*)d_in[15];
    const float* bng = (const float*)d_in[16];
    const float* bnb = (const float*)d_in[17];
    const float* bnm = (const float*)d_in[18];
    const float* bnv = (const float*)d_in[19];

    const int N = in_sizes[0];
    const int E = in_sizes[2];
    const int G = out_size / (12 * EMB);
    const int M_pad = ((N + 63) / 64) * 64;
    const int MT = M_pad / 64;
    const int nb = (N + 1023) / 1024;

    char* ws = (char*)d_ws;
    size_t off = 0;
    auto alloc = [&](size_t bytes) -> void* {
        void* p = (void*)(ws + off);
        off += (bytes + 255) & ~(size_t)255;
        return p;
    };
    unsigned short* Fb0  = (unsigned short*)alloc((size_t)M_pad * FS * 2);  // bf16 feats ping
    unsigned short* Fb1  = (unsigned short*)alloc((size_t)M_pad * FS * 2);  // bf16 feats pong
    unsigned short* A1   = (unsigned short*)alloc((size_t)M_pad * FS * 2);  // agg (MLP input)
    unsigned short* W1P  = (unsigned short*)alloc((size_t)NL * 40 * KS1 * 64 * 8 * 2);
    unsigned short* W2P  = (unsigned short*)alloc((size_t)NL * 20 * KS2 * 64 * 8 * 2);
    float*          b1p  = (float*)alloc((size_t)NL * HS * 4);
    float*          scp  = (float*)alloc((size_t)NL * FS * 4);
    float*          shp  = (float*)alloc((size_t)NL * FS * 4);
    int*            deg  = (int*)alloc((size_t)N * 4);
    int*            roff = (int*)alloc(((size_t)N + 1) * 4);
    int*            curs = (int*)alloc((size_t)N * 4);
    int*            srcs = (int*)alloc((size_t)E * 4);
    int*            cnt9 = (int*)alloc((size_t)N * 9 * 4);
    int*            incl = (int*)alloc((size_t)N * 4);
    int*            part = (int*)alloc((size_t)1024 * 4);
    int*            gst  = (int*)alloc(((size_t)G + 1) * 4);

    // weight / param prep (fragment-packed)
    {
        int t1 = NL * 40 * KS1 * 64;
        k_prep_w1p<<<(t1 + 255) / 256, 256, 0, stream>>>(W1, W1P, t1);
        int t2 = NL * 20 * KS2 * 64;
        k_prep_w2p<<<(t2 + 255) / 256, 256, 0, stream>>>(W2, W2P, t2);
        int t3 = NL * HS;
        k_prep_params<<<(t3 + 255) / 256, 256, 0, stream>>>(b1, b2, bng, bnb, bnm, bnv,
                                                            b1p, scp, shp, t3);
    }

    // h0 (bf16)
    {
        int tt = N * (FS / 4);
        k_init_h0<<<(tt + 255) / 256, 256, 0, stream>>>(an, ch, ne0, ne1, Fb0, N);
    }

    // CSR by dst + categorical counts (hierarchical scan) + graph bounds
    hipMemsetAsync(deg, 0, (size_t)N * 4, stream);
    hipMemsetAsync(cnt9, 0, (size_t)N * 9 * 4, stream);
    k_hist<<<(E + 255) / 256, 256, 0, stream>>>(dst, bt, bd, deg, cnt9, E);
    k_scan_blk<<<nb, 256, 0, stream>>>(deg, incl, part, N);
    k_scan_part<<<1, 1024, 0, stream>>>(part, nb);
    k_scan_add<<<(N + 255) / 256, 256, 0, stream>>>(incl, part, deg, roff, curs, N);
    k_scatter<<<(E + 255) / 256, 256, 0, stream>>>(dst, src, curs, srcs, E);
    k_gbound<<<(N + 255) / 256, 256, 0, stream>>>(gid, gst, N, G);

    const int aggBlocks = (N + 4 * NPW - 1) / (4 * NPW);

    unsigned short* Fbc = Fb0;
    unsigned short* Fbo = Fb1;
    for (int l = 0; l < NL; ++l) {
        k_pool<<<G, 256, 0, stream>>>(Fbc, gst, (float*)d_out, l);
        k_aggregate<<<aggBlocks, 256, 0, stream>>>(Fbc,
                                                   ee0 + (size_t)l * 6 * EMB,
                                                   ee1 + (size_t)l * 3 * EMB,
                                                   roff, srcs, cnt9, A1, N);
        const unsigned short* W1Pl = W1P + (size_t)l * 40 * KS1 * 64 * 8;
        const unsigned short* W2Pl = W2P + (size_t)l * 20 * KS2 * 64 * 8;
        if (l < NL - 1)
            k_mlp<1><<<MT, 512, 0, stream>>>(A1, W1Pl, W2Pl,
                                             b1p + (size_t)l * HS,
                                             scp + (size_t)l * FS, shp + (size_t)l * FS,
                                             Fbo);
        else
            k_mlp<2><<<MT, 512, 0, stream>>>(A1, W1Pl, W2Pl,
                                             b1p + (size_t)l * HS,
                                             scp + (size_t)l * FS, shp + (size_t)l * FS,
                                             Fbo);
        unsigned short* t = Fbc; Fbc = Fbo; Fbo = t;
    }
    k_pool<<<G, 256, 0, stream>>>(Fbc, gst, (float*)d_out, NL);
}

// Round 18
// 657.280 us; speedup vs baseline: 1.0625x; 1.0500x over previous
//
#include <hip/hip_runtime.h>

#define EMB 300
#define HID 600
#define NL 5
#define BN_EPS 1e-5f

#define FS 320          // padded feature stride (300 -> 320); row = 640 B
#define HS 640          // padded hidden stride (600 -> 640)
#define NPW 8           // nodes per wave in aggregate
#define KS1 10          // GEMM1 K-steps (320/32)
#define KS2 20          // GEMM2 K-steps (640/32)

typedef __attribute__((ext_vector_type(8))) short short8;
typedef __attribute__((ext_vector_type(4))) float f32x4;
typedef __attribute__((ext_vector_type(4))) unsigned short us4;

__device__ __forceinline__ unsigned short f2bf(float x) {
    unsigned u = __float_as_uint(x);
    unsigned r = (u + 0x7FFFu + ((u >> 16) & 1u)) >> 16;   // RNE
    return (unsigned short)r;
}
__device__ __forceinline__ float bf2f(unsigned short h) {
    return __uint_as_float(((unsigned)h) << 16);
}

#define GLDS16(gsrc, ldst)                                                     \
    __builtin_amdgcn_global_load_lds(                                          \
        (const __attribute__((address_space(1))) unsigned int*)(gsrc),         \
        (__attribute__((address_space(3))) unsigned int*)(ldst), 16, 0, 0)

// pinned-issue 16B weight load (prefetch the compiler refuses to schedule)
#define GLOAD8(dst, ptr)                                                       \
    asm volatile("global_load_dwordx4 %0, %1, off" : "=v"(dst) : "v"(ptr))

// ---------------- h0 = node_emb0[an] + node_emb1[ch] -> bf16, stride FS ----------------
__global__ void k_init_h0(const int* __restrict__ an, const int* __restrict__ ch,
                          const float* __restrict__ ne0, const float* __restrict__ ne1,
                          unsigned short* __restrict__ Fb, int n) {
    int t = blockIdx.x * blockDim.x + threadIdx.x;
    int i = t / (FS / 4), f4 = t - i * (FS / 4);
    if (i >= n) return;
    int f = f4 * 4;
    us4 h = {0, 0, 0, 0};
    if (f < EMB) {  // EMB=300 is a multiple of 4; rows are 16B-aligned
        const float4 a = *(const float4*)(ne0 + (size_t)an[i] * EMB + f);
        const float4 b = *(const float4*)(ne1 + (size_t)ch[i] * EMB + f);
        h[0] = f2bf(a.x + b.x); h[1] = f2bf(a.y + b.y);
        h[2] = f2bf(a.z + b.z); h[3] = f2bf(a.w + b.w);
    }
    *(us4*)(Fb + (size_t)i * FS + f) = h;
}

// ---------------- CSR build (by dst) + per-node categorical counts [N][9] ----------------
__global__ void k_hist(const int* __restrict__ dst, const int* __restrict__ bt,
                       const int* __restrict__ bd, int* __restrict__ deg,
                       int* __restrict__ cnt9, int e) {
    int t = blockIdx.x * blockDim.x + threadIdx.x;
    if (t >= e) return;
    int d = dst[t];
    atomicAdd(&deg[d], 1);
    atomicAdd(&cnt9[d * 9 + bt[t]], 1);
    atomicAdd(&cnt9[d * 9 + 6 + bd[t]], 1);
}

// ---- hierarchical scan: pass A ----
__global__ __launch_bounds__(256)
void k_scan_blk(const int* __restrict__ deg, int* __restrict__ incl,
                int* __restrict__ part, int n) {
    int tid = threadIdx.x;
    int base = blockIdx.x * 1024 + tid * 4;
    int v0 = (base + 0 < n) ? deg[base + 0] : 0;
    int v1 = (base + 1 < n) ? deg[base + 1] : 0;
    int v2 = (base + 2 < n) ? deg[base + 2] : 0;
    int v3 = (base + 3 < n) ? deg[base + 3] : 0;
    int ts = v0 + v1 + v2 + v3;
    int lane = tid & 63, w = tid >> 6;
    int x = ts;
#pragma unroll
    for (int off = 1; off < 64; off <<= 1) {
        int y = __shfl_up(x, off);
        if (lane >= off) x += y;
    }
    __shared__ int ws[4];
    if (lane == 63) ws[w] = x;
    __syncthreads();
    int woff = 0;
    for (int i = 0; i < w; ++i) woff += ws[i];
    int r = woff + x - ts;
    r += v0; if (base + 0 < n) incl[base + 0] = r;
    r += v1; if (base + 1 < n) incl[base + 1] = r;
    r += v2; if (base + 2 < n) incl[base + 2] = r;
    r += v3; if (base + 3 < n) incl[base + 3] = r;
    if (tid == 255) part[blockIdx.x] = woff + x;
}

// ---- pass B ----
__global__ __launch_bounds__(1024)
void k_scan_part(int* __restrict__ part, int nb) {
    int tid = threadIdx.x;
    int v = (tid < nb) ? part[tid] : 0;
    int lane = tid & 63, w = tid >> 6;
    int x = v;
#pragma unroll
    for (int off = 1; off < 64; off <<= 1) {
        int y = __shfl_up(x, off);
        if (lane >= off) x += y;
    }
    __shared__ int ws[16];
    if (lane == 63) ws[w] = x;
    __syncthreads();
    int woff = 0;
    for (int i = 0; i < w; ++i) woff += ws[i];
    if (tid < nb) part[tid] = woff + x - v;
}

// ---- pass C ----
__global__ void k_scan_add(const int* __restrict__ incl, const int* __restrict__ part,
                           const int* __restrict__ deg, int* __restrict__ roff,
                           int* __restrict__ curs, int n) {
    int i = blockIdx.x * blockDim.x + threadIdx.x;
    if (i >= n) return;
    int inc = incl[i] + part[i >> 10];
    roff[i + 1] = inc;
    curs[i] = inc - deg[i];
    if (i == 0) roff[0] = 0;
}

__global__ void k_scatter(const int* __restrict__ dst, const int* __restrict__ src,
                          int* __restrict__ cursor, int* __restrict__ srcs, int e) {
    int t = blockIdx.x * blockDim.x + threadIdx.x;
    if (t < e) { int p = atomicAdd(&cursor[dst[t]], 1); srcs[p] = src[t]; }
}

// ---- graph boundaries ----
__global__ void k_gbound(const int* __restrict__ gids, int* __restrict__ gstart,
                         int n, int G) {
    int i = blockIdx.x * blockDim.x + threadIdx.x;
    if (i >= n) return;
    int g = gids[i];
    int gp = (i == 0) ? -1 : gids[i - 1];
    for (int q = gp + 1; q <= g; ++q) gstart[q] = i;
    if (i == n - 1)
        for (int q = g + 1; q <= G; ++q) gstart[q] = n;
}

// ---------------- weight prep: MFMA-fragment-packed bf16 weights ----------------
__global__ void k_prep_w1p(const float* __restrict__ W1, unsigned short* __restrict__ W1P,
                           int total) {
    int t = blockIdx.x * blockDim.x + threadIdx.x;
    if (t >= total) return;
    int lane = t & 63;
    int r = t >> 6;
    int ks = r % KS1; r /= KS1;
    int nf = r % 40;
    int l = r / 40;
    int n = nf * 16 + (lane & 15);
    int kb = ks * 32 + (lane >> 4) * 8;
    unsigned short v[8];
#pragma unroll
    for (int e = 0; e < 8; ++e) {
        int k = kb + e;
        v[e] = (n < HID && k < EMB) ? f2bf(W1[(size_t)l * EMB * HID + (size_t)k * HID + n]) : 0;
    }
    *(short8*)(W1P + (size_t)t * 8) = *(short8*)v;
}

__global__ void k_prep_w2p(const float* __restrict__ W2, unsigned short* __restrict__ W2P,
                           int total) {
    int t = blockIdx.x * blockDim.x + threadIdx.x;
    if (t >= total) return;
    int lane = t & 63;
    int r = t >> 6;
    int ks = r % KS2; r /= KS2;
    int nf = r % 20;
    int l = r / 20;
    int n = nf * 16 + (lane & 15);
    int kb = ks * 32 + (lane >> 4) * 8;
    unsigned short v[8];
#pragma unroll
    for (int e = 0; e < 8; ++e) {
        int k = kb + e;
        v[e] = (n < EMB && k < HID) ? f2bf(W2[(size_t)l * HID * EMB + (size_t)k * EMB + n]) : 0;
    }
    *(short8*)(W2P + (size_t)t * 8) = *(short8*)v;
}

__global__ void k_prep_params(const float* __restrict__ b1, const float* __restrict__ b2,
                              const float* __restrict__ g, const float* __restrict__ be,
                              const float* __restrict__ mu, const float* __restrict__ va,
                              float* __restrict__ b1p, float* __restrict__ scp,
                              float* __restrict__ shp, int total) {
    int t = blockIdx.x * blockDim.x + threadIdx.x;
    if (t >= total) return;
    int n = t % HS, l = t / HS;
    b1p[t] = (n < HID) ? b1[l * HID + n] : 0.f;
    if (n < FS) {
        float sc = 0.f, sh = 0.f;
        if (n < EMB) {
            sc = g[l * EMB + n] * rsqrtf(va[l * EMB + n] + BN_EPS);
            sh = be[l * EMB + n] + (b2[l * EMB + n] - mu[l * EMB + n]) * sc;
        }
        scp[l * FS + n] = sc;
        shp[l * FS + n] = sh;
    }
}

// ---------------- fused aggregate + pool (one dispatch per layer) ----------------
// blocks [0, aggBlocks): aggregation (8 nodes/wave, batched CSR via lane loads + shfl)
// blocks [aggBlocks, aggBlocks+G): per-graph pooling (4 waves per graph)
__global__ __launch_bounds__(256)
void k_agg_pool(const unsigned short* __restrict__ fb,   // feats bf16 [M_pad][FS]
                const float* __restrict__ e0, const float* __restrict__ e1,
                const int* __restrict__ roff, const int* __restrict__ srcs,
                const int* __restrict__ cnt9,
                unsigned short* __restrict__ agg, int n,
                const int* __restrict__ gstart, float* __restrict__ out, int l,
                int aggBlocks) {
    const int lane = threadIdx.x & 63;
    if ((int)blockIdx.x < aggBlocks) {
        // ================= aggregation =================
        const int v0 = (blockIdx.x * 4 + (threadIdx.x >> 6)) * NPW;
        if (v0 >= n) return;
        const int nv = min(NPW, n - v0);

        int rv = 0;
        {
            int idx = v0 + lane;
            if (lane <= NPW && idx <= n) rv = roff[idx];
        }
        const int base = __shfl(rv, 0);
        const int total = __shfl(rv, nv) - base;

        const int n9 = n * 9;
        const int base9 = v0 * 9;
        int c0 = (base9 + lane < n9) ? cnt9[base9 + lane] : 0;
        int c1 = (lane < 8 && base9 + 64 + lane < n9) ? cnt9[base9 + 64 + lane] : 0;

        int c = 0;
        int chunk = 0;
        auto nextIdx = [&]() -> int {
            if ((c & 63) == 0)
                chunk = (c + lane < total) ? srcs[base + c + lane] : 0;
            int r = __shfl(chunk, c & 63);
            ++c;
            return r;
        };

#pragma unroll
        for (int i = 0; i < NPW; ++i) {
            if (i < nv) {
                const int di = __shfl(rv, i + 1) - __shfl(rv, i);
                float aA[4] = {0.f, 0.f, 0.f, 0.f};
                float aB[4] = {0.f, 0.f, 0.f, 0.f};
                int k = 0;
                for (; k + 4 <= di; k += 4) {
                    int i0 = nextIdx(), i1 = nextIdx(), i2 = nextIdx(), i3 = nextIdx();
                    const us4* r0 = (const us4*)(fb + (size_t)i0 * FS);
                    const us4* r1 = (const us4*)(fb + (size_t)i1 * FS);
                    const us4* r2 = (const us4*)(fb + (size_t)i2 * FS);
                    const us4* r3 = (const us4*)(fb + (size_t)i3 * FS);
                    us4 x0 = r0[lane], x1 = r1[lane], x2 = r2[lane], x3 = r3[lane];
                    us4 y0 = {}, y1 = {}, y2 = {}, y3 = {};
                    if (lane < 11) { y0 = r0[64 + lane]; y1 = r1[64 + lane];
                                     y2 = r2[64 + lane]; y3 = r3[64 + lane]; }
#pragma unroll
                    for (int q = 0; q < 4; ++q)
                        aA[q] += (bf2f(x0[q]) + bf2f(x1[q])) + (bf2f(x2[q]) + bf2f(x3[q]));
                    if (lane < 11) {
#pragma unroll
                        for (int q = 0; q < 4; ++q)
                            aB[q] += (bf2f(y0[q]) + bf2f(y1[q])) + (bf2f(y2[q]) + bf2f(y3[q]));
                    }
                }
                for (; k < di; ++k) {
                    int i0 = nextIdx();
                    const us4* r0 = (const us4*)(fb + (size_t)i0 * FS);
                    us4 x0 = r0[lane];
#pragma unroll
                    for (int q = 0; q < 4; ++q) aA[q] += bf2f(x0[q]);
                    if (lane < 11) {
                        us4 y0 = r0[64 + lane];
#pragma unroll
                        for (int q = 0; q < 4; ++q) aB[q] += bf2f(y0[q]);
                    }
                }
#pragma unroll
                for (int t = 0; t < 9; ++t) {
                    const int pos = i * 9 + t;
                    int cv = __shfl(pos < 64 ? c0 : c1, pos & 63);
                    if (cv) {
                        float fc = (float)cv;
                        const float* row = (t < 6) ? (e0 + t * EMB) : (e1 + (t - 6) * EMB);
                        f32x4 ea = *(const f32x4*)(row + 4 * lane);
#pragma unroll
                        for (int q = 0; q < 4; ++q) aA[q] += fc * ea[q];
                        if (lane < 11) {
                            f32x4 eb = *(const f32x4*)(row + 256 + 4 * lane);
#pragma unroll
                            for (int q = 0; q < 4; ++q) aB[q] += fc * eb[q];
                        }
                    }
                }
                us4* ar = (us4*)(agg + (size_t)(v0 + i) * FS);
                us4 h;
#pragma unroll
                for (int q = 0; q < 4; ++q) h[q] = f2bf(aA[q]);
                ar[lane] = h;
                if (lane < 11) {
                    us4 hb;
#pragma unroll
                    for (int q = 0; q < 4; ++q) hb[q] = f2bf(aB[q]);
                    ar[64 + lane] = hb;
                }
            }
        }
    } else {
        // ================= per-graph pooling =================
        const int g = blockIdx.x - aggBlocks;
        const int w = threadIdx.x >> 6;
        const int s = gstart[g], e = gstart[g + 1];
        float aA[4] = {0.f, 0.f, 0.f, 0.f};
        float aB[4] = {0.f, 0.f, 0.f, 0.f};
        int v = s + w;
        for (; v + 4 < e; v += 8) {
            const us4* r0 = (const us4*)(fb + (size_t)v * FS);
            const us4* r1 = (const us4*)(fb + (size_t)(v + 4) * FS);
            us4 x0 = r0[lane], x1 = r1[lane];
            us4 y0 = {}, y1 = {};
            if (lane < 11) { y0 = r0[64 + lane]; y1 = r1[64 + lane]; }
#pragma unroll
            for (int q = 0; q < 4; ++q) aA[q] += bf2f(x0[q]) + bf2f(x1[q]);
            if (lane < 11) {
#pragma unroll
                for (int q = 0; q < 4; ++q) aB[q] += bf2f(y0[q]) + bf2f(y1[q]);
            }
        }
        if (v < e) {
            const us4* r0 = (const us4*)(fb + (size_t)v * FS);
            us4 x0 = r0[lane];
#pragma unroll
            for (int q = 0; q < 4; ++q) aA[q] += bf2f(x0[q]);
            if (lane < 11) {
                us4 y0 = r0[64 + lane];
#pragma unroll
                for (int q = 0; q < 4; ++q) aB[q] += bf2f(y0[q]);
            }
        }
        __shared__ f32x4 smA[4][64];
        __shared__ f32x4 smB[4][16];
        f32x4 xa;
#pragma unroll
        for (int q = 0; q < 4; ++q) xa[q] = aA[q];
        smA[w][lane] = xa;
        if (lane < 16) {
            f32x4 xb;
#pragma unroll
            for (int q = 0; q < 4; ++q) xb[q] = aB[q];
            smB[w][lane] = xb;
        }
        __syncthreads();
        if (w == 0) {
            f32x4 t = smA[0][lane] + smA[1][lane] + smA[2][lane] + smA[3][lane];
            float inv = 1.0f / fmaxf((float)(e - s), 1.0f);
            float* oavg = out + (size_t)g * (12 * EMB) + l * EMB;
            float* osum = oavg + 6 * EMB;
            *(f32x4*)(oavg + 4 * lane) = t * inv;
            *(f32x4*)(osum + 4 * lane) = t;
            if (lane < 11) {
                f32x4 tb = smB[0][lane] + smB[1][lane] + smB[2][lane] + smB[3][lane];
                *(f32x4*)(oavg + 256 + 4 * lane) = tb * inv;
                *(f32x4*)(osum + 256 + 4 * lane) = tb;
            }
        }
    }
}

// ---------------- standalone per-graph pooling (final layer) ----------------
__global__ __launch_bounds__(256)
void k_pool(const unsigned short* __restrict__ feats, const int* __restrict__ gstart,
            float* __restrict__ out, int l) {
    const int g = blockIdx.x;
    const int tid = threadIdx.x;
    const int w = tid >> 6, lane = tid & 63;
    const int s = gstart[g], e = gstart[g + 1];
    float aA[4] = {0.f, 0.f, 0.f, 0.f};
    float aB[4] = {0.f, 0.f, 0.f, 0.f};
    int v = s + w;
    for (; v + 4 < e; v += 8) {
        const us4* r0 = (const us4*)(feats + (size_t)v * FS);
        const us4* r1 = (const us4*)(feats + (size_t)(v + 4) * FS);
        us4 x0 = r0[lane], x1 = r1[lane];
        us4 y0 = {}, y1 = {};
        if (lane < 11) { y0 = r0[64 + lane]; y1 = r1[64 + lane]; }
#pragma unroll
        for (int q = 0; q < 4; ++q) aA[q] += bf2f(x0[q]) + bf2f(x1[q]);
        if (lane < 11) {
#pragma unroll
            for (int q = 0; q < 4; ++q) aB[q] += bf2f(y0[q]) + bf2f(y1[q]);
        }
    }
    if (v < e) {
        const us4* r0 = (const us4*)(feats + (size_t)v * FS);
        us4 x0 = r0[lane];
#pragma unroll
        for (int q = 0; q < 4; ++q) aA[q] += bf2f(x0[q]);
        if (lane < 11) {
            us4 y0 = r0[64 + lane];
#pragma unroll
            for (int q = 0; q < 4; ++q) aB[q] += bf2f(y0[q]);
        }
    }
    __shared__ f32x4 smA[4][64];
    __shared__ f32x4 smB[4][16];
    f32x4 xa;
#pragma unroll
    for (int q = 0; q < 4; ++q) xa[q] = aA[q];
    smA[w][lane] = xa;
    if (lane < 16) {
        f32x4 xb;
#pragma unroll
        for (int q = 0; q < 4; ++q) xb[q] = aB[q];
        smB[w][lane] = xb;
    }
    __syncthreads();
    if (w == 0) {
        f32x4 t = smA[0][lane] + smA[1][lane] + smA[2][lane] + smA[3][lane];
        float inv = 1.0f / fmaxf((float)(e - s), 1.0f);
        float* oavg = out + (size_t)g * (12 * EMB) + l * EMB;
        float* osum = oavg + 6 * EMB;
        *(f32x4*)(oavg + 4 * lane) = t * inv;
        *(f32x4*)(osum + 4 * lane) = t;
        if (lane < 11) {
            f32x4 tb = smB[0][lane] + smB[1][lane] + smB[2][lane] + smB[3][lane];
            *(f32x4*)(oavg + 256 + 4 * lane) = tb * inv;
            *(f32x4*)(osum + 256 + 4 * lane) = tb;
        }
    }
}

// ---------------- fused MLP (R11 structure + asm-pinned weight prefetch) ----------------
// One block per 64-row strip; 512 threads (8 waves). A-strip + H in XOR-swizzled
// LDS. Weight fragments double-buffered in named register sets wA/wB via
// asm-volatile global_load_dwordx4 (issue order pinned), consumed under counted
// s_waitcnt vmcnt(5) + sched_barrier(0). (512,2) for register headroom.
// EPI 1: BN + relu; EPI 2: BN only (last layer).
template <int EPI>
__global__ __launch_bounds__(512, 2)
void k_mlp(const unsigned short* __restrict__ A,     // [M_pad][FS] bf16
           const unsigned short* __restrict__ W1P,   // [40][KS1][64][8]
           const unsigned short* __restrict__ W2P,   // [20][KS2][64][8]
           const float* __restrict__ b1p,            // [HS]
           const float* __restrict__ scp, const float* __restrict__ shp,  // [FS]
           unsigned short* __restrict__ Cout) {      // [M_pad][FS] bf16
    __shared__ unsigned short Ash[64 * 320];   // 40 KB, swizzled
    __shared__ unsigned short Hsh[64 * 640];   // 80 KB, swizzled
    const int tid = threadIdx.x;
    const int lane = tid & 63, wid = tid >> 6;
    const int lr = lane & 15, lk = lane >> 4, rgrp = lk * 4;
    const size_t m0s = (size_t)blockIdx.x * 64;
    const int swz = (lr & 7) << 4;

    // ---- stage A strip (swizzled) ----
#pragma unroll
    for (int cch = 0; cch < 5; ++cch) {
        const int sbase = wid * 5120 + cch * 1024;
        const int s = sbase + lane * 16;
        const int row = s / 640;
        const int u = s ^ ((row & 7) << 4);   // involution within the row
        GLDS16((const char*)A + m0s * 640 + u, (char*)Ash + sbase);
    }

    // ---- GEMM1 weight pointers + preload ks=0 (overlaps A-stage drain) ----
    const unsigned short* p1[5];
#pragma unroll
    for (int i = 0; i < 5; ++i)
        p1[i] = W1P + (((size_t)(wid * 5 + i) * KS1) * 64 + lane) * 8;
    short8 wA0, wA1, wA2, wA3, wA4, wB0, wB1, wB2, wB3, wB4;
    GLOAD8(wA0, p1[0]); GLOAD8(wA1, p1[1]); GLOAD8(wA2, p1[2]);
    GLOAD8(wA3, p1[3]); GLOAD8(wA4, p1[4]);

    asm volatile("s_waitcnt vmcnt(0)" ::: "memory");
    __builtin_amdgcn_sched_barrier(0);
    __syncthreads();

    // ---- GEMM1: H[64][640] = relu(A x W1 + b1); wave wid owns cols wid*80..+80 ----
    f32x4 acc1[5][4] = {};
    {
#pragma unroll
        for (int kk = 0; kk < 5; ++kk) {
            {   // even ks = 2kk; prefetch ks+1 into wB
                const int ks = 2 * kk;
                GLOAD8(wB0, p1[0] + (ks + 1) * 512); GLOAD8(wB1, p1[1] + (ks + 1) * 512);
                GLOAD8(wB2, p1[2] + (ks + 1) * 512); GLOAD8(wB3, p1[3] + (ks + 1) * 512);
                GLOAD8(wB4, p1[4] + (ks + 1) * 512);
                asm volatile("s_waitcnt vmcnt(5)" ::: "memory");
                __builtin_amdgcn_sched_barrier(0);
                short8 a[4];
#pragma unroll
                for (int j = 0; j < 4; ++j) {
                    const int o = ((j * 16 + lr) * 640 + ks * 64 + lk * 16) ^ swz;
                    a[j] = *(const short8*)((const char*)Ash + o);
                }
                __builtin_amdgcn_s_setprio(1);
#pragma unroll
                for (int j = 0; j < 4; ++j) {
                    acc1[0][j] = __builtin_amdgcn_mfma_f32_16x16x32_bf16(wA0, a[j], acc1[0][j], 0, 0, 0);
                    acc1[1][j] = __builtin_amdgcn_mfma_f32_16x16x32_bf16(wA1, a[j], acc1[1][j], 0, 0, 0);
                    acc1[2][j] = __builtin_amdgcn_mfma_f32_16x16x32_bf16(wA2, a[j], acc1[2][j], 0, 0, 0);
                    acc1[3][j] = __builtin_amdgcn_mfma_f32_16x16x32_bf16(wA3, a[j], acc1[3][j], 0, 0, 0);
                    acc1[4][j] = __builtin_amdgcn_mfma_f32_16x16x32_bf16(wA4, a[j], acc1[4][j], 0, 0, 0);
                }
                __builtin_amdgcn_s_setprio(0);
            }
            {   // odd ks = 2kk+1; prefetch ks+1 into wA (unless done)
                const int ks = 2 * kk + 1;
                if (ks + 1 < KS1) {
                    GLOAD8(wA0, p1[0] + (ks + 1) * 512); GLOAD8(wA1, p1[1] + (ks + 1) * 512);
                    GLOAD8(wA2, p1[2] + (ks + 1) * 512); GLOAD8(wA3, p1[3] + (ks + 1) * 512);
                    GLOAD8(wA4, p1[4] + (ks + 1) * 512);
                    asm volatile("s_waitcnt vmcnt(5)" ::: "memory");
                } else {
                    asm volatile("s_waitcnt vmcnt(0)" ::: "memory");
                }
                __builtin_amdgcn_sched_barrier(0);
                short8 a[4];
#pragma unroll
                for (int j = 0; j < 4; ++j) {
                    const int o = ((j * 16 + lr) * 640 + ks * 64 + lk * 16) ^ swz;
                    a[j] = *(const short8*)((const char*)Ash + o);
                }
                __builtin_amdgcn_s_setprio(1);
#pragma unroll
                for (int j = 0; j < 4; ++j) {
                    acc1[0][j] = __builtin_amdgcn_mfma_f32_16x16x32_bf16(wB0, a[j], acc1[0][j], 0, 0, 0);
                    acc1[1][j] = __builtin_amdgcn_mfma_f32_16x16x32_bf16(wB1, a[j], acc1[1][j], 0, 0, 0);
                    acc1[2][j] = __builtin_amdgcn_mfma_f32_16x16x32_bf16(wB2, a[j], acc1[2][j], 0, 0, 0);
                    acc1[3][j] = __builtin_amdgcn_mfma_f32_16x16x32_bf16(wB3, a[j], acc1[3][j], 0, 0, 0);
                    acc1[4][j] = __builtin_amdgcn_mfma_f32_16x16x32_bf16(wB4, a[j], acc1[4][j], 0, 0, 0);
                }
                __builtin_amdgcn_s_setprio(0);
            }
        }
    }

    // epilogue 1 -> Hsh (swizzled)
#pragma unroll
    for (int i = 0; i < 5; ++i) {
        const int n0 = wid * 80 + i * 16 + rgrp;
        const f32x4 q0 = *(const f32x4*)&b1p[n0];
#pragma unroll
        for (int j = 0; j < 4; ++j) {
            const int m = j * 16 + lr;
            us4 h;
#pragma unroll
            for (int p = 0; p < 4; ++p)
                h[p] = f2bf(fmaxf(acc1[i][j][p] + q0[p], 0.f));
            const int o = (m * 1280 + n0 * 2) ^ swz;
            *(us4*)((char*)Hsh + o) = h;
        }
    }

    // ---- GEMM2 weight pointers + preload ks=0 (overlaps the barrier) ----
    const int wm2 = wid >> 2, wn2 = wid & 3;   // 2 x 4: 32 rows x 80 cols per wave
    const unsigned short* p2[5];
#pragma unroll
    for (int i = 0; i < 5; ++i)
        p2[i] = W2P + (((size_t)(wn2 * 5 + i) * KS2) * 64 + lane) * 8;
    GLOAD8(wA0, p2[0]); GLOAD8(wA1, p2[1]); GLOAD8(wA2, p2[2]);
    GLOAD8(wA3, p2[3]); GLOAD8(wA4, p2[4]);
    __syncthreads();

    // ---- GEMM2: F'[64][320] = BN(H[64][640] x W2); 2x4 grid ----
    {
        const int r0 = wm2 * 32 + lr;
        f32x4 acc2[5][2] = {};
#pragma unroll
        for (int kk = 0; kk < 10; ++kk) {
            {   // even ks = 2kk; prefetch ks+1 into wB
                const int ks = 2 * kk;
                GLOAD8(wB0, p2[0] + (ks + 1) * 512); GLOAD8(wB1, p2[1] + (ks + 1) * 512);
                GLOAD8(wB2, p2[2] + (ks + 1) * 512); GLOAD8(wB3, p2[3] + (ks + 1) * 512);
                GLOAD8(wB4, p2[4] + (ks + 1) * 512);
                asm volatile("s_waitcnt vmcnt(5)" ::: "memory");
                __builtin_amdgcn_sched_barrier(0);
                const int oh0 = (r0 * 1280 + ks * 64 + lk * 16) ^ swz;
                const int oh1 = ((r0 + 16) * 1280 + ks * 64 + lk * 16) ^ swz;
                short8 h0 = *(const short8*)((const char*)Hsh + oh0);
                short8 h1 = *(const short8*)((const char*)Hsh + oh1);
                __builtin_amdgcn_s_setprio(1);
                acc2[0][0] = __builtin_amdgcn_mfma_f32_16x16x32_bf16(wA0, h0, acc2[0][0], 0, 0, 0);
                acc2[0][1] = __builtin_amdgcn_mfma_f32_16x16x32_bf16(wA0, h1, acc2[0][1], 0, 0, 0);
                acc2[1][0] = __builtin_amdgcn_mfma_f32_16x16x32_bf16(wA1, h0, acc2[1][0], 0, 0, 0);
                acc2[1][1] = __builtin_amdgcn_mfma_f32_16x16x32_bf16(wA1, h1, acc2[1][1], 0, 0, 0);
                acc2[2][0] = __builtin_amdgcn_mfma_f32_16x16x32_bf16(wA2, h0, acc2[2][0], 0, 0, 0);
                acc2[2][1] = __builtin_amdgcn_mfma_f32_16x16x32_bf16(wA2, h1, acc2[2][1], 0, 0, 0);
                acc2[3][0] = __builtin_amdgcn_mfma_f32_16x16x32_bf16(wA3, h0, acc2[3][0], 0, 0, 0);
                acc2[3][1] = __builtin_amdgcn_mfma_f32_16x16x32_bf16(wA3, h1, acc2[3][1], 0, 0, 0);
                acc2[4][0] = __builtin_amdgcn_mfma_f32_16x16x32_bf16(wA4, h0, acc2[4][0], 0, 0, 0);
                acc2[4][1] = __builtin_amdgcn_mfma_f32_16x16x32_bf16(wA4, h1, acc2[4][1], 0, 0, 0);
                __builtin_amdgcn_s_setprio(0);
            }
            {   // odd ks = 2kk+1; prefetch ks+1 into wA (unless done)
                const int ks = 2 * kk + 1;
                if (ks + 1 < KS2) {
                    GLOAD8(wA0, p2[0] + (ks + 1) * 512); GLOAD8(wA1, p2[1] + (ks + 1) * 512);
                    GLOAD8(wA2, p2[2] + (ks + 1) * 512); GLOAD8(wA3, p2[3] + (ks + 1) * 512);
                    GLOAD8(wA4, p2[4] + (ks + 1) * 512);
                    asm volatile("s_waitcnt vmcnt(5)" ::: "memory");
                } else {
                    asm volatile("s_waitcnt vmcnt(0)" ::: "memory");
                }
                __builtin_amdgcn_sched_barrier(0);
                const int oh0 = (r0 * 1280 + ks * 64 + lk * 16) ^ swz;
                const int oh1 = ((r0 + 16) * 1280 + ks * 64 + lk * 16) ^ swz;
                short8 h0 = *(const short8*)((const char*)Hsh + oh0);
                short8 h1 = *(const short8*)((const char*)Hsh + oh1);
                __builtin_amdgcn_s_setprio(1);
                acc2[0][0] = __builtin_amdgcn_mfma_f32_16x16x32_bf16(wB0, h0, acc2[0][0], 0, 0, 0);
                acc2[0][1] = __builtin_amdgcn_mfma_f32_16x16x32_bf16(wB0, h1, acc2[0][1], 0, 0, 0);
                acc2[1][0] = __builtin_amdgcn_mfma_f32_16x16x32_bf16(wB1, h0, acc2[1][0], 0, 0, 0);
                acc2[1][1] = __builtin_amdgcn_mfma_f32_16x16x32_bf16(wB1, h1, acc2[1][1], 0, 0, 0);
                acc2[2][0] = __builtin_amdgcn_mfma_f32_16x16x32_bf16(wB2, h0, acc2[2][0], 0, 0, 0);
                acc2[2][1] = __builtin_amdgcn_mfma_f32_16x16x32_bf16(wB2, h1, acc2[2][1], 0, 0, 0);
                acc2[3][0] = __builtin_amdgcn_mfma_f32_16x16x32_bf16(wB3, h0, acc2[3][0], 0, 0, 0);
                acc2[3][1] = __builtin_amdgcn_mfma_f32_16x16x32_bf16(wB3, h1, acc2[3][1], 0, 0, 0);
                acc2[4][0] = __builtin_amdgcn_mfma_f32_16x16x32_bf16(wB4, h0, acc2[4][0], 0, 0, 0);
                acc2[4][1] = __builtin_amdgcn_mfma_f32_16x16x32_bf16(wB4, h1, acc2[4][1], 0, 0, 0);
                __builtin_amdgcn_s_setprio(0);
            }
        }
        // epilogue 2 -> global
#pragma unroll
        for (int i = 0; i < 5; ++i) {
            const int n0 = wn2 * 80 + i * 16 + rgrp;    // < 320
            const f32x4 q0 = *(const f32x4*)&scp[n0];
            const f32x4 q1 = *(const f32x4*)&shp[n0];
#pragma unroll
            for (int j = 0; j < 2; ++j) {
                const size_t m = m0s + (size_t)(wm2 * 32 + j * 16 + lr);
                us4 h;
#pragma unroll
                for (int p = 0; p < 4; ++p) {
                    float x = acc2[i][j][p] * q0[p] + q1[p];
                    if (EPI == 1) x = fmaxf(x, 0.f);
                    h[p] = f2bf(x);
                }
                *(us4*)(Cout + m * FS + n0) = h;
            }
        }
    }
}

extern "C" void kernel_launch(void* const* d_in, const int* in_sizes, int n_in,
                              void* d_out, int out_size, void* d_ws, size_t ws_size,
                              hipStream_t stream) {
    const int*   an  = (const int*)d_in[0];
    const int*   ch  = (const int*)d_in[1];
    const int*   bt  = (const int*)d_in[2];
    const int*   bd  = (const int*)d_in[3];
    const int*   src = (const int*)d_in[4];
    const int*   dst = (const int*)d_in[5];
    const int*   gid = (const int*)d_in[6];
    const float* ne0 = (const float*)d_in[8];
    const float* ne1 = (const float*)d_in[9];
    const float* ee0 = (const float*)d_in[10];
    const float* ee1 = (const float*)d_in[11];
    const float* W1  = (const float*)d_in[12];
    const float* b1  = (const float*)d_in[13];
    const float* W2  = (const float*)d_in[14];
    const float* b2  = (const float*)d_in[15];
    const float* bng = (const float*)d_in[16];
    const float* bnb = (const float*)d_in[17];
    const float* bnm = (const float*)d_in[18];
    const float* bnv = (const float*)d_in[19];

    const int N = in_sizes[0];
    const int E = in_sizes[2];
    const int G = out_size / (12 * EMB);
    const int M_pad = ((N + 63) / 64) * 64;
    const int MT = M_pad / 64;
    const int nb = (N + 1023) / 1024;

    char* ws = (char*)d_ws;
    size_t off = 0;
    auto alloc = [&](size_t bytes) -> void* {
        void* p = (void*)(ws + off);
        off += (bytes + 255) & ~(size_t)255;
        return p;
    };
    unsigned short* Fb0  = (unsigned short*)alloc((size_t)M_pad * FS * 2);  // bf16 feats ping
    unsigned short* Fb1  = (unsigned short*)alloc((size_t)M_pad * FS * 2);  // bf16 feats pong
    unsigned short* A1   = (unsigned short*)alloc((size_t)M_pad * FS * 2);  // agg (MLP input)
    unsigned short* W1P  = (unsigned short*)alloc((size_t)NL * 40 * KS1 * 64 * 8 * 2);
    unsigned short* W2P  = (unsigned short*)alloc((size_t)NL * 20 * KS2 * 64 * 8 * 2);
    float*          b1p  = (float*)alloc((size_t)NL * HS * 4);
    float*          scp  = (float*)alloc((size_t)NL * FS * 4);
    float*          shp  = (float*)alloc((size_t)NL * FS * 4);
    int*            deg  = (int*)alloc((size_t)N * 4);
    int*            roff = (int*)alloc(((size_t)N + 1) * 4);
    int*            curs = (int*)alloc((size_t)N * 4);
    int*            srcs = (int*)alloc((size_t)E * 4);
    int*            cnt9 = (int*)alloc((size_t)N * 9 * 4);
    int*            incl = (int*)alloc((size_t)N * 4);
    int*            part = (int*)alloc((size_t)1024 * 4);
    int*            gst  = (int*)alloc(((size_t)G + 1) * 4);

    // weight / param prep (fragment-packed)
    {
        int t1 = NL * 40 * KS1 * 64;
        k_prep_w1p<<<(t1 + 255) / 256, 256, 0, stream>>>(W1, W1P, t1);
        int t2 = NL * 20 * KS2 * 64;
        k_prep_w2p<<<(t2 + 255) / 256, 256, 0, stream>>>(W2, W2P, t2);
        int t3 = NL * HS;
        k_prep_params<<<(t3 + 255) / 256, 256, 0, stream>>>(b1, b2, bng, bnb, bnm, bnv,
                                                            b1p, scp, shp, t3);
    }

    // h0 (bf16)
    {
        int tt = N * (FS / 4);
        k_init_h0<<<(tt + 255) / 256, 256, 0, stream>>>(an, ch, ne0, ne1, Fb0, N);
    }

    // CSR by dst + categorical counts (hierarchical scan) + graph bounds
    hipMemsetAsync(deg, 0, (size_t)N * 4, stream);
    hipMemsetAsync(cnt9, 0, (size_t)N * 9 * 4, stream);
    k_hist<<<(E + 255) / 256, 256, 0, stream>>>(dst, bt, bd, deg, cnt9, E);
    k_scan_blk<<<nb, 256, 0, stream>>>(deg, incl, part, N);
    k_scan_part<<<1, 1024, 0, stream>>>(part, nb);
    k_scan_add<<<(N + 255) / 256, 256, 0, stream>>>(incl, part, deg, roff, curs, N);
    k_scatter<<<(E + 255) / 256, 256, 0, stream>>>(dst, src, curs, srcs, E);
    k_gbound<<<(N + 255) / 256, 256, 0, stream>>>(gid, gst, N, G);

    const int aggBlocks = (N + 4 * NPW - 1) / (4 * NPW);

    unsigned short* Fbc = Fb0;
    unsigned short* Fbo = Fb1;
    for (int l = 0; l < NL; ++l) {
        k_agg_pool<<<aggBlocks + G, 256, 0, stream>>>(Fbc,
                                                      ee0 + (size_t)l * 6 * EMB,
                                                      ee1 + (size_t)l * 3 * EMB,
                                                      roff, srcs, cnt9, A1, N,
                                                      gst, (float*)d_out, l, aggBlocks);
        const unsigned short* W1Pl = W1P + (size_t)l * 40 * KS1 * 64 * 8;
        const unsigned short* W2Pl = W2P + (size_t)l * 20 * KS2 * 64 * 8;
        if (l < NL - 1)
            k_mlp<1><<<MT, 512, 0, stream>>>(A1, W1Pl, W2Pl,
                                             b1p + (size_t)l * HS,
                                             scp + (size_t)l * FS, shp + (size_t)l * FS,
                                             Fbo);
        else
            k_mlp<2><<<MT, 512, 0, stream>>>(A1, W1Pl, W2Pl,
                                             b1p + (size_t)l * HS,
                                             scp + (size_t)l * FS, shp + (size_t)l * FS,
                                             Fbo);
        unsigned short* t = Fbc; Fbc = Fbo; Fbo = t;
    }
    k_pool<<<G, 256, 0, stream>>>(Fbc, gst, (float*)d_out, NL);
}